// Round 3
// baseline (226.263 us; speedup 1.0000x reference)
//
#include <hip/hip_runtime.h>
#include <math.h>

#define NROWS 4096
#define D 128
#define SPC 8
#define KRET 7
#define MARGIN 0.2f
#define NTILE (NROWS / 128)      // 32 column tiles
#define CPR (NTILE * KRET)       // 224 candidates per row
#define LDP 132                  // padded LDS stride (floats), keeps float4 16B-aligned

typedef unsigned long long u64;

__device__ __forceinline__ u64 minu(u64 a, u64 b) { return a < b ? a : b; }

// ws layout (floats):
//   [0] loss_sum, [1] count
//   [4096 .. 8191]   diag
//   [8192 .. 40959]  posd  (4096 x 8 f32; slot i&7 of row i unused)
//   [40960 .. ]      cand  (u64, 4096 x 224) -- byte offset 163840, 8B-aligned
// Fallback path: [0],[1] accum, [2..2+NROWS) diag.

__global__ __launch_bounds__(256) void diag_kernel(const float* __restrict__ emb,
                                                   const float* __restrict__ emb1,
                                                   float* __restrict__ diag) {
    int wave = threadIdx.x >> 6;
    int lane = threadIdx.x & 63;
    int row = blockIdx.x * 4 + wave;
    const float* a = emb + (size_t)row * D;
    const float* b = emb1 + (size_t)row * D;
    float s = a[lane] * b[lane] + a[lane + 64] * b[lane + 64];
    for (int off = 32; off > 0; off >>= 1) s += __shfl_down(s, off, 64);
    if (lane == 0) diag[row] = s;
}

// ---- Distance tile + fused per-tile top-7 selection ----
// Tile 128x128, K split in two 64-chunks (LDS ~68 KB -> 2 blocks/CU).
__global__ __launch_bounds__(256) void dist_kernel(const float* __restrict__ emb,
                                                   const float* __restrict__ emb1,
                                                   const int* __restrict__ labels,
                                                   const int* __restrict__ labels1,
                                                   const float* __restrict__ diag,
                                                   float* __restrict__ posd,
                                                   u64* __restrict__ cand) {
    __shared__ float sA[64 * LDP];   // sA[k*LDP + row] = emb[i0+row][p*64+k]
    __shared__ float sB[64 * LDP];
    __shared__ float sdA[128], sdB[128];
    __shared__ int sLi[128], sLj[128];

    const int t = threadIdx.x;
    const int i0 = blockIdx.y * 128, j0 = blockIdx.x * 128;

    if (t < 128) { sdA[t] = diag[i0 + t]; sLi[t] = labels1[i0 + t]; }
    else         { sdB[t - 128] = diag[j0 + t - 128]; sLj[t - 128] = labels[j0 + t - 128]; }

    const int tx = t & 15, ty = t >> 4;
    const int r0 = 4 * ty, c0 = 4 * tx;

    float acc[8][8];
#pragma unroll
    for (int r = 0; r < 8; ++r)
#pragma unroll
        for (int c = 0; c < 8; ++c) acc[r][c] = 0.f;

    for (int p = 0; p < 2; ++p) {
        if (p) __syncthreads();      // phase-0 reads done before restage
        // stage 64 k's of A and B: float4 global loads, scalar transposed LDS stores
#pragma unroll
        for (int n = 0; n < 8; ++n) {
            int fidx = n * 256 + t;
            int row = fidx >> 4;
            int kk = (fidx & 15) * 4;
            float4 va = *(const float4*)(emb  + (size_t)(i0 + row) * D + p * 64 + kk);
            float4 vb = *(const float4*)(emb1 + (size_t)(j0 + row) * D + p * 64 + kk);
            sA[(kk + 0) * LDP + row] = va.x;
            sA[(kk + 1) * LDP + row] = va.y;
            sA[(kk + 2) * LDP + row] = va.z;
            sA[(kk + 3) * LDP + row] = va.w;
            sB[(kk + 0) * LDP + row] = vb.x;
            sB[(kk + 1) * LDP + row] = vb.y;
            sB[(kk + 2) * LDP + row] = vb.z;
            sB[(kk + 3) * LDP + row] = vb.w;
        }
        __syncthreads();

#pragma unroll 4
        for (int k = 0; k < 64; ++k) {
            const float* a = sA + k * LDP;
            const float* b = sB + k * LDP;
            float4 a0 = *(const float4*)(a + r0);
            float4 a1 = *(const float4*)(a + r0 + 64);
            float4 b0 = *(const float4*)(b + c0);
            float4 b1 = *(const float4*)(b + c0 + 64);
            float av[8] = {a0.x, a0.y, a0.z, a0.w, a1.x, a1.y, a1.z, a1.w};
            float bv[8] = {b0.x, b0.y, b0.z, b0.w, b1.x, b1.y, b1.z, b1.w};
#pragma unroll
            for (int r = 0; r < 8; ++r)
#pragma unroll
                for (int c = 0; c < 8; ++c)
                    acc[r][c] = fmaf(av[r], bv[c], acc[r][c]);
        }
    }

    // ---- epilogue: distances, posd capture, per-tile top-7 per row ----
    const int tj = j0 >> 7;
#pragma unroll
    for (int rr = 0; rr < 8; ++rr) {
        const int row = (rr < 4) ? (r0 + rr) : (64 + r0 + rr - 4);
        const int gi = i0 + row;
        const float di = sdA[row];
        const int li = sLi[row];
        u64 pk[8];
#pragma unroll
        for (int c = 0; c < 8; ++c) {
            const int col = (c < 4) ? (c0 + c) : (64 + c0 + c - 4);
            const int gj = j0 + col;
            float dist = sqrtf(fmaxf(di + sdB[col] - 2.f * acc[rr][c], 1e-4f));
            bool pos = (sLj[col] == li) && (gj != gi);
            if (pos) posd[(size_t)gi * SPC + (gj & (SPC - 1))] = dist;
            float score = dist + (pos ? 1e6f : 0.f);
            pk[c] = ((u64)__float_as_uint(score) << 32) | (unsigned)gj;
        }
        // 7 rounds of argmin across this row's 128 cols (16 lanes x 8 each)
        u64 myw = 0;
#pragma unroll
        for (int r = 0; r < KRET; ++r) {
            u64 m = pk[0];
#pragma unroll
            for (int c = 1; c < 8; ++c) m = minu(m, pk[c]);
            m = minu(m, __shfl_xor(m, 1, 64));
            m = minu(m, __shfl_xor(m, 2, 64));
            m = minu(m, __shfl_xor(m, 4, 64));
            m = minu(m, __shfl_xor(m, 8, 64));
            if (tx == r) myw = m;   // lane tx keeps winner r
#pragma unroll
            for (int c = 0; c < 8; ++c) pk[c] = (pk[c] == m) ? ~0ull : pk[c];
        }
        if (tx < KRET) cand[(size_t)gi * CPR + tj * KRET + tx] = myw;
    }
}

// ---- Merge 32 per-tile top-7s -> global top-7, validity, loss. Wave per row. ----
__global__ __launch_bounds__(256) void merge_kernel(const float* __restrict__ emb,
                                                    const float* __restrict__ posd,
                                                    const u64* __restrict__ cand,
                                                    float* __restrict__ ws_acc) {
    const int lane = threadIdx.x & 63;
    const int i = blockIdx.x * 4 + (threadIdx.x >> 6);
    const u64* cr = cand + (size_t)i * CPR;
    u64 e0 = cr[lane];
    u64 e1 = cr[lane + 64];
    u64 e2 = cr[lane + 128];
    u64 e3 = (lane < CPR - 192) ? cr[lane + 192] : ~0ull;   // guard: don't read next row

    u64 w[KRET];
#pragma unroll
    for (int r = 0; r < KRET; ++r) {
        u64 m = minu(minu(e0, e1), minu(e2, e3));
#pragma unroll
        for (int off = 1; off < 64; off <<= 1) m = minu(m, __shfl_xor(m, off, 64));
        w[r] = m;
        e0 = (e0 == m) ? ~0ull : e0;
        e1 = (e1 == m) ? ~0ull : e1;
        e2 = (e2 == m) ? ~0ull : e2;
        e3 = (e3 == m) ? ~0ull : e3;
    }

    // sort the 7 winners by column index: repack (idx<<32)|distbits, Batcher-8 network
    u64 s[8];
#pragma unroll
    for (int r = 0; r < KRET; ++r) s[r] = (w[r] << 32) | (w[r] >> 32);
    s[7] = ~0ull;
#define CE(x, y) { u64 lo = minu(s[x], s[y]); u64 hi = s[x] ^ s[y] ^ lo; s[x] = lo; s[y] = hi; }
    CE(0,1) CE(2,3) CE(4,5) CE(6,7)
    CE(0,2) CE(1,3) CE(4,6) CE(5,7)
    CE(1,2) CE(5,6)
    CE(0,4) CE(1,5) CE(2,6) CE(3,7)
    CE(2,4) CE(3,5)
    CE(1,2) CE(3,4) CE(5,6)
#undef CE

    const int ig = i & (SPC - 1);
    float ls = 0.f, cnt = 0.f;
    bool any = false;
    bool v[KRET];
    int nidx[KRET];
#pragma unroll
    for (int k = 0; k < KRET; ++k) {
        nidx[k] = (int)(s[k] >> 32);
        float dneg = __uint_as_float((unsigned)(s[k] & 0xffffffffu));
        int m = k + (k >= ig ? 1 : 0);
        float dp = posd[(size_t)i * SPC + m];
        v[k] = dp < dneg + MARGIN;     // wave-uniform
        any = any || v[k];
    }

    if (any) {
        const float a0 = emb[(size_t)i * D + lane];
        const float a1 = emb[(size_t)i * D + 64 + lane];
#pragma unroll
        for (int k = 0; k < KRET; ++k) {
            if (v[k]) {                 // wave-uniform branch
                int m = k + (k >= ig ? 1 : 0);
                int tp = (i & ~(SPC - 1)) + m;
                int tn = nidx[k];
                float d0 = emb[(size_t)tp * D + lane] - a0;
                float d1 = emb[(size_t)tp * D + 64 + lane] - a1;
                float sp = d0 * d0 + d1 * d1;
                float g0 = emb[(size_t)tn * D + lane] - a0;
                float g1 = emb[(size_t)tn * D + 64 + lane] - a1;
                float sn = g0 * g0 + g1 * g1;
#pragma unroll
                for (int off = 1; off < 64; off <<= 1) {
                    sp += __shfl_xor(sp, off, 64);
                    sn += __shfl_xor(sn, off, 64);
                }
                float dap = sqrtf(sp + 1e-8f);
                float dan = sqrtf(sn + 1e-8f);
                ls += (dap + MARGIN) + fmaxf(MARGIN - dan, 0.f);
                cnt += 1.f;
            }
        }
    }
    if (lane == 0 && cnt != 0.f) {
        atomicAdd(&ws_acc[0], ls);
        atomicAdd(&ws_acc[1], cnt);
    }
}

// ---------------- Fallback (round-1 fused kernel, used only if ws too small) ----------------
__global__ __launch_bounds__(256) void main_kernel(const float* __restrict__ emb,
                                                   const float* __restrict__ emb1,
                                                   const int* __restrict__ labels,
                                                   const int* __restrict__ labels1,
                                                   const float* __restrict__ diag,
                                                   float* __restrict__ ws_acc) {
    const int i = blockIdx.x;
    const int tid = threadIdx.x;

    __shared__ float s_anchor[D];
    __shared__ float s_posd[SPC];
    __shared__ unsigned long long s_red[4];
    __shared__ unsigned long long s_win;
    __shared__ int s_negidx[KRET];
    __shared__ float s_negd[KRET];
    __shared__ float s_dreal[2 * KRET];

    if (tid < D) s_anchor[tid] = emb[(size_t)i * D + tid];
    __syncthreads();

    const float diag_i = diag[i];
    const int li = labels1[i];

    float score[16];
#pragma unroll
    for (int it = 0; it < 16; ++it) {
        int j = it * 256 + tid;
        const float4* r = (const float4*)(emb1 + (size_t)j * D);
        float acc = 0.f;
#pragma unroll
        for (int q = 0; q < D / 4; ++q) {
            float4 vv = r[q];
            acc = fmaf(vv.x, s_anchor[4 * q + 0], acc);
            acc = fmaf(vv.y, s_anchor[4 * q + 1], acc);
            acc = fmaf(vv.z, s_anchor[4 * q + 2], acc);
            acc = fmaf(vv.w, s_anchor[4 * q + 3], acc);
        }
        float d2 = diag_i + diag[j] - 2.f * acc;
        float dist = sqrtf(fmaxf(d2, 1e-4f));
        bool is_pos = (labels[j] == li) && (j != i);
        if (is_pos) s_posd[j & (SPC - 1)] = dist;
        score[it] = dist + (is_pos ? 1e6f : 0.f);
    }
    __syncthreads();

    for (int r = 0; r < KRET; ++r) {
        unsigned long long best = ~0ull;
#pragma unroll
        for (int it = 0; it < 16; ++it) {
            unsigned long long p =
                ((unsigned long long)__float_as_uint(score[it]) << 32) |
                (unsigned int)(it * 256 + tid);
            best = best < p ? best : p;
        }
        for (int off = 32; off > 0; off >>= 1) {
            unsigned long long o = __shfl_down(best, off, 64);
            best = best < o ? best : o;
        }
        if ((tid & 63) == 0) s_red[tid >> 6] = best;
        __syncthreads();
        if (tid == 0) {
            unsigned long long w = s_red[0];
            w = w < s_red[1] ? w : s_red[1];
            w = w < s_red[2] ? w : s_red[2];
            w = w < s_red[3] ? w : s_red[3];
            s_win = w;
        }
        __syncthreads();
        unsigned long long w = s_win;
        int cj = (int)(w & 0xffffffffu);
        if (tid == (cj & 255)) score[cj >> 8] = 1e30f;
        if (tid == 0) {
            s_negidx[r] = cj;
            s_negd[r] = __uint_as_float((unsigned int)(w >> 32));
        }
        __syncthreads();
    }

    if (tid == 0) {
        for (int a = 1; a < KRET; ++a) {
            int ix = s_negidx[a]; float dv = s_negd[a];
            int b = a - 1;
            while (b >= 0 && s_negidx[b] > ix) {
                s_negidx[b + 1] = s_negidx[b];
                s_negd[b + 1] = s_negd[b];
                --b;
            }
            s_negidx[b + 1] = ix; s_negd[b + 1] = dv;
        }
    }
    __syncthreads();

    {
        int wave = tid >> 6, lane = tid & 63;
        int gb = i & ~(SPC - 1);
        for (int p = wave; p < 2 * KRET; p += 4) {
            int tgt;
            if (p < KRET) {
                int k = p;
                int m = k + (k >= (i & (SPC - 1)) ? 1 : 0);
                tgt = gb + m;
            } else {
                tgt = s_negidx[p - KRET];
            }
            float d0 = emb[(size_t)tgt * D + lane]      - s_anchor[lane];
            float d1 = emb[(size_t)tgt * D + 64 + lane] - s_anchor[64 + lane];
            float s = d0 * d0 + d1 * d1;
            for (int off = 32; off > 0; off >>= 1) s += __shfl_down(s, off, 64);
            if (lane == 0) s_dreal[p] = sqrtf(s + 1e-8f);
        }
    }
    __syncthreads();

    if (tid == 0) {
        float ls = 0.f, cnt = 0.f;
        for (int k = 0; k < KRET; ++k) {
            int m = k + (k >= (i & (SPC - 1)) ? 1 : 0);
            float dpos = s_posd[m];
            float dneg = s_negd[k];
            if (dpos < dneg + MARGIN) {
                float d_ap = s_dreal[k];
                float d_an = s_dreal[KRET + k];
                ls += (d_ap + MARGIN) + fmaxf(MARGIN - d_an, 0.f);
                cnt += 1.f;
            }
        }
        if (ls != 0.f) atomicAdd(&ws_acc[0], ls);
        if (cnt != 0.f) atomicAdd(&ws_acc[1], cnt);
    }
}

__global__ void finalize_kernel(const float* __restrict__ ws_acc, float* __restrict__ out) {
    float ls = ws_acc[0], cnt = ws_acc[1];
    out[0] = cnt > 0.f ? ls / cnt : ls;
}

extern "C" void kernel_launch(void* const* d_in, const int* in_sizes, int n_in,
                              void* d_out, int out_size, void* d_ws, size_t ws_size,
                              hipStream_t stream) {
    const float* emb     = (const float*)d_in[0];
    const int*   labels  = (const int*)d_in[1];
    const float* emb1    = (const float*)d_in[2];
    const int*   labels1 = (const int*)d_in[3];
    float* ws = (float*)d_ws;

    hipMemsetAsync(d_ws, 0, 2 * sizeof(float), stream);

    size_t need = (size_t)40960 * sizeof(float) + (size_t)NROWS * CPR * sizeof(u64);
    if (ws_size >= need) {
        float* diag = ws + 4096;
        float* posd = ws + 8192;
        u64*   cand = (u64*)(ws + 40960);
        diag_kernel<<<NROWS / 4, 256, 0, stream>>>(emb, emb1, diag);
        dim3 grid(NROWS / 128, NROWS / 128);
        dist_kernel<<<grid, 256, 0, stream>>>(emb, emb1, labels, labels1, diag, posd, cand);
        merge_kernel<<<NROWS / 4, 256, 0, stream>>>(emb, posd, cand, ws);
        finalize_kernel<<<1, 1, 0, stream>>>(ws, (float*)d_out);
    } else {
        float* diag = ws + 2;
        diag_kernel<<<NROWS / 4, 256, 0, stream>>>(emb, emb1, diag);
        main_kernel<<<NROWS, 256, 0, stream>>>(emb, emb1, labels, labels1, diag, ws);
        finalize_kernel<<<1, 1, 0, stream>>>(ws, (float*)d_out);
    }
}

// Round 4
// 185.724 us; speedup vs baseline: 1.2183x; 1.2183x over previous
//
#include <hip/hip_runtime.h>
#include <math.h>

#define NROWS 4096
#define D 128
#define SPC 8
#define KRET 7
#define MARGIN 0.2f
#define NTILE 32              // 4096/128 column tiles
#define CPT 14                // candidates per (row, tile): 2 halves x top-7
#define CPR (NTILE * CPT)     // 448 candidates per row

typedef unsigned long long u64;
typedef __attribute__((ext_vector_type(8))) short short8;   // 8 bf16 (4 VGPRs)
typedef __attribute__((ext_vector_type(4))) float f32x4;    // MFMA accumulator

__device__ __forceinline__ u64 minu(u64 a, u64 b) { return a < b ? a : b; }

// bf16 round-to-nearest-even split helpers (bit-exact, header-independent)
__device__ __forceinline__ ushort f2bf_rne(float x) {
    unsigned u = __float_as_uint(x);
    unsigned r = (u + 0x7fffu + ((u >> 16) & 1u)) >> 16;
    return (ushort)r;
}
__device__ __forceinline__ float bf2f(ushort h) {
    return __uint_as_float((unsigned)h << 16);
}

// ws layout (floats):
//   [0..1]              loss_sum, count accums
//   [4096 .. 8191]      diag
//   [8192 .. 40959]     posd (4096 x 8 f32)
//   [40960 .. ]         embH (4096x128 ushort = 262144 f)
//   [303104 .. ]        embL
//   [565248 .. ]        emb1H
//   [827392 .. ]        emb1L
//   [1089536 .. ]       cand (u64, 4096 x 448)
// Fallback path: [0],[1] accum, [2..2+NROWS) diag.

// ---- prep: bf16 hi/lo split of both matrices + Gram diagonal ----
__global__ __launch_bounds__(256) void prep_kernel(const float* __restrict__ emb,
                                                   const float* __restrict__ emb1,
                                                   ushort* __restrict__ embH, ushort* __restrict__ embL,
                                                   ushort* __restrict__ emb1H, ushort* __restrict__ emb1L,
                                                   float* __restrict__ diag) {
    const int lane = threadIdx.x & 63;
    const int row = blockIdx.x * 4 + (threadIdx.x >> 6);
    const size_t base = (size_t)row * D + 2 * lane;
    const float2 a = *(const float2*)(emb + base);
    const float2 b = *(const float2*)(emb1 + base);

    ushort ah0 = f2bf_rne(a.x), ah1 = f2bf_rne(a.y);
    ushort al0 = f2bf_rne(a.x - bf2f(ah0)), al1 = f2bf_rne(a.y - bf2f(ah1));
    ushort bh0 = f2bf_rne(b.x), bh1 = f2bf_rne(b.y);
    ushort bl0 = f2bf_rne(b.x - bf2f(bh0)), bl1 = f2bf_rne(b.y - bf2f(bh1));

    *(ushort2*)(embH + base)  = make_ushort2(ah0, ah1);
    *(ushort2*)(embL + base)  = make_ushort2(al0, al1);
    *(ushort2*)(emb1H + base) = make_ushort2(bh0, bh1);
    *(ushort2*)(emb1L + base) = make_ushort2(bl0, bl1);

    float s = a.x * b.x + a.y * b.y;
#pragma unroll
    for (int off = 1; off < 64; off <<= 1) s += __shfl_xor(s, off, 64);
    if (lane == 0) diag[row] = s;
}

// ---- dist tile via 3-term bf16-split MFMA + fused per-tile top-7 ----
// 128x128 tile, 4 waves, each wave 64x64 output via 16x16x32 MFMAs.
// LDS tiles [128][72] bf16 (pad 72 -> stride 144B, bank-quad stride 9 == 1 mod 8: conflict-free).
__global__ __launch_bounds__(256, 2) void dist_mfma(const ushort* __restrict__ embH, const ushort* __restrict__ embL,
                                                    const ushort* __restrict__ emb1H, const ushort* __restrict__ emb1L,
                                                    const int* __restrict__ labels, const int* __restrict__ labels1,
                                                    const float* __restrict__ diag,
                                                    float* __restrict__ posd, u64* __restrict__ cand) {
    __shared__ ushort smem[36864];        // 73728 B: AH|AL|BH|BL [128][72] bf16 each
    __shared__ float sdA[128], sdB[128];
    __shared__ int sLi[128], sLj[128];
    ushort* AH = smem;
    ushort* AL = smem + 9216;
    ushort* BH = smem + 18432;
    ushort* BL = smem + 27648;
    float* distbuf = (float*)(void*)smem;  // [128][132] f32 (67584 B), overlays staging after k-loop

    const int t = threadIdx.x;
    const int i0 = blockIdx.y * 128, j0 = blockIdx.x * 128;

    if (t < 128) { sdA[t] = diag[i0 + t]; sLi[t] = labels1[i0 + t]; }
    else         { sdB[t - 128] = diag[j0 + t - 128]; sLj[t - 128] = labels[j0 + t - 128]; }

    const int w = t >> 6, l = t & 63;
    const int R = (w >> 1) * 64, C = (w & 1) * 64;
    const int lr = l & 15, lg = l >> 4;

    f32x4 acc[4][4];
#pragma unroll
    for (int m = 0; m < 4; ++m)
#pragma unroll
        for (int n = 0; n < 4; ++n) acc[m][n] = (f32x4){0.f, 0.f, 0.f, 0.f};

    const int srow = t & 127;              // staging row; c chunks below -> (row+c) mod 8 uniform
    for (int p = 0; p < 2; ++p) {
        if (p) __syncthreads();            // phase-0 LDS reads complete before restage
#pragma unroll
        for (int n = 0; n < 4; ++n) {
            const int c = n * 2 + (t >> 7);                         // 0..7
            const size_t gA = (size_t)(i0 + srow) * D + p * 64 + c * 8;
            const size_t gB = (size_t)(j0 + srow) * D + p * 64 + c * 8;
            const int ld = srow * 72 + c * 8;
            *(uint4*)(AH + ld) = *(const uint4*)(embH + gA);
            *(uint4*)(AL + ld) = *(const uint4*)(embL + gA);
            *(uint4*)(BH + ld) = *(const uint4*)(emb1H + gB);
            *(uint4*)(BL + ld) = *(const uint4*)(emb1L + gB);
        }
        __syncthreads();

#pragma unroll
        for (int ks = 0; ks < 2; ++ks) {
            const int koff = ks * 32 + lg * 8;
            short8 ah[4], al4[4], bh[4], bl4[4];
#pragma unroll
            for (int m = 0; m < 4; ++m) {
                const int ra = (R + 16 * m + lr) * 72 + koff;
                ah[m]  = *(const short8*)(AH + ra);
                al4[m] = *(const short8*)(AL + ra);
                const int rb = (C + 16 * m + lr) * 72 + koff;
                bh[m]  = *(const short8*)(BH + rb);
                bl4[m] = *(const short8*)(BL + rb);
            }
#pragma unroll
            for (int m = 0; m < 4; ++m)
#pragma unroll
                for (int n = 0; n < 4; ++n) {
                    acc[m][n] = __builtin_amdgcn_mfma_f32_16x16x32_bf16(ah[m],  bh[n],  acc[m][n], 0, 0, 0);
                    acc[m][n] = __builtin_amdgcn_mfma_f32_16x16x32_bf16(ah[m],  bl4[n], acc[m][n], 0, 0, 0);
                    acc[m][n] = __builtin_amdgcn_mfma_f32_16x16x32_bf16(al4[m], bh[n],  acc[m][n], 0, 0, 0);
                }
        }
    }
    __syncthreads();   // all LDS frag reads done; staging area becomes distbuf

    // epilogue: scores -> distbuf, posd capture.
    // C/D layout (m89-verified): col = lane&15, row = (lane>>4)*4 + reg
#pragma unroll
    for (int m = 0; m < 4; ++m)
#pragma unroll
        for (int n = 0; n < 4; ++n)
#pragma unroll
            for (int r = 0; r < 4; ++r) {
                const int row = R + 16 * m + 4 * lg + r;
                const int col = C + 16 * n + lr;
                const float v = acc[m][n][r];
                const float dist = sqrtf(fmaxf(sdA[row] + sdB[col] - 2.f * v, 1e-4f));
                const int gi = i0 + row, gj = j0 + col;
                const bool pos = (sLj[col] == sLi[row]) && (gi != gj);
                if (pos) posd[(size_t)gi * SPC + (gj & (SPC - 1))] = dist;
                distbuf[row * 132 + col] = dist + (pos ? 1e6f : 0.f);
            }
    __syncthreads();

    // selection: 2 threads per row, register insertion-scan of 64 scores each
    {
        const int row = t >> 1, h = t & 1;
        u64 s[KRET];
#pragma unroll
        for (int k = 0; k < KRET; ++k) s[k] = ~0ull;
        const float* dr = distbuf + row * 132 + 64 * h;
        for (int c = 0; c < 64; ++c) {
            const int cc = (c + row) & 63;            // diagonal stagger: conflict-free reads
            const float v = dr[cc];
            const u64 pk = ((u64)__float_as_uint(v) << 32) | (unsigned)(j0 + 64 * h + cc);
            if (pk < s[KRET - 1]) {
                u64 tmp = pk;
#pragma unroll
                for (int k = 0; k < KRET; ++k) {
                    const u64 lo = minu(s[k], tmp);
                    tmp = s[k] ^ tmp ^ lo;
                    s[k] = lo;
                }
            }
        }
        u64* cw = cand + (size_t)(i0 + row) * CPR + (j0 >> 7) * CPT + h * KRET;
#pragma unroll
        for (int k = 0; k < KRET; ++k) cw[k] = s[k];
    }
}

// ---- merge 448 candidates/row -> global top-7, validity, loss. Wave per row. ----
__global__ __launch_bounds__(256) void merge_kernel(const float* __restrict__ emb,
                                                    const float* __restrict__ posd,
                                                    const u64* __restrict__ cand,
                                                    float* __restrict__ ws_acc) {
    const int lane = threadIdx.x & 63;
    const int i = blockIdx.x * 4 + (threadIdx.x >> 6);
    const u64* cr = cand + (size_t)i * CPR;
    u64 e[7];
#pragma unroll
    for (int q = 0; q < 7; ++q) e[q] = cr[q * 64 + lane];

    u64 w[KRET];
#pragma unroll
    for (int r = 0; r < KRET; ++r) {
        u64 m = e[0];
#pragma unroll
        for (int q = 1; q < 7; ++q) m = minu(m, e[q]);
#pragma unroll
        for (int off = 1; off < 64; off <<= 1) m = minu(m, __shfl_xor(m, off, 64));
        w[r] = m;
#pragma unroll
        for (int q = 0; q < 7; ++q) e[q] = (e[q] == m) ? ~0ull : e[q];
    }

    // sort winners by column index: repack (idx<<32)|distbits, Batcher-8
    u64 s[8];
#pragma unroll
    for (int r = 0; r < KRET; ++r) s[r] = (w[r] << 32) | (w[r] >> 32);
    s[7] = ~0ull;
#define CE(x, y) { u64 lo = minu(s[x], s[y]); u64 hi = s[x] ^ s[y] ^ lo; s[x] = lo; s[y] = hi; }
    CE(0,1) CE(2,3) CE(4,5) CE(6,7)
    CE(0,2) CE(1,3) CE(4,6) CE(5,7)
    CE(1,2) CE(5,6)
    CE(0,4) CE(1,5) CE(2,6) CE(3,7)
    CE(2,4) CE(3,5)
    CE(1,2) CE(3,4) CE(5,6)
#undef CE

    const int ig = i & (SPC - 1);
    float ls = 0.f, cnt = 0.f;
    bool any = false;
    bool v[KRET];
    int nidx[KRET];
#pragma unroll
    for (int k = 0; k < KRET; ++k) {
        nidx[k] = (int)(s[k] >> 32);
        const float dneg = __uint_as_float((unsigned)(s[k] & 0xffffffffu));
        const int m = k + (k >= ig ? 1 : 0);
        const float dp = posd[(size_t)i * SPC + m];
        v[k] = dp < dneg + MARGIN;       // wave-uniform
        any = any || v[k];
    }

    if (any) {
        const float a0 = emb[(size_t)i * D + lane];
        const float a1 = emb[(size_t)i * D + 64 + lane];
#pragma unroll
        for (int k = 0; k < KRET; ++k) {
            if (v[k]) {
                const int m = k + (k >= ig ? 1 : 0);
                const int tp = (i & ~(SPC - 1)) + m;
                const int tn = nidx[k];
                float d0 = emb[(size_t)tp * D + lane] - a0;
                float d1 = emb[(size_t)tp * D + 64 + lane] - a1;
                float sp = d0 * d0 + d1 * d1;
                float g0 = emb[(size_t)tn * D + lane] - a0;
                float g1 = emb[(size_t)tn * D + 64 + lane] - a1;
                float sn = g0 * g0 + g1 * g1;
#pragma unroll
                for (int off = 1; off < 64; off <<= 1) {
                    sp += __shfl_xor(sp, off, 64);
                    sn += __shfl_xor(sn, off, 64);
                }
                ls += (sqrtf(sp + 1e-8f) + MARGIN) + fmaxf(MARGIN - sqrtf(sn + 1e-8f), 0.f);
                cnt += 1.f;
            }
        }
    }
    if (lane == 0 && cnt != 0.f) {
        atomicAdd(&ws_acc[0], ls);
        atomicAdd(&ws_acc[1], cnt);
    }
}

// ---------------- Fallback path (round-1, only if ws too small) ----------------
__global__ __launch_bounds__(256) void diag_kernel(const float* __restrict__ emb,
                                                   const float* __restrict__ emb1,
                                                   float* __restrict__ diag) {
    int wave = threadIdx.x >> 6;
    int lane = threadIdx.x & 63;
    int row = blockIdx.x * 4 + wave;
    const float* a = emb + (size_t)row * D;
    const float* b = emb1 + (size_t)row * D;
    float s = a[lane] * b[lane] + a[lane + 64] * b[lane + 64];
    for (int off = 32; off > 0; off >>= 1) s += __shfl_down(s, off, 64);
    if (lane == 0) diag[row] = s;
}

__global__ __launch_bounds__(256) void main_kernel(const float* __restrict__ emb,
                                                   const float* __restrict__ emb1,
                                                   const int* __restrict__ labels,
                                                   const int* __restrict__ labels1,
                                                   const float* __restrict__ diag,
                                                   float* __restrict__ ws_acc) {
    const int i = blockIdx.x;
    const int tid = threadIdx.x;
    __shared__ float s_anchor[D];
    __shared__ float s_posd[SPC];
    __shared__ u64 s_red[4];
    __shared__ u64 s_win;
    __shared__ int s_negidx[KRET];
    __shared__ float s_negd[KRET];
    __shared__ float s_dreal[2 * KRET];

    if (tid < D) s_anchor[tid] = emb[(size_t)i * D + tid];
    __syncthreads();
    const float diag_i = diag[i];
    const int li = labels1[i];
    float score[16];
#pragma unroll
    for (int it = 0; it < 16; ++it) {
        int j = it * 256 + tid;
        const float4* r = (const float4*)(emb1 + (size_t)j * D);
        float acc = 0.f;
#pragma unroll
        for (int q = 0; q < D / 4; ++q) {
            float4 vv = r[q];
            acc = fmaf(vv.x, s_anchor[4 * q + 0], acc);
            acc = fmaf(vv.y, s_anchor[4 * q + 1], acc);
            acc = fmaf(vv.z, s_anchor[4 * q + 2], acc);
            acc = fmaf(vv.w, s_anchor[4 * q + 3], acc);
        }
        float d2 = diag_i + diag[j] - 2.f * acc;
        float dist = sqrtf(fmaxf(d2, 1e-4f));
        bool is_pos = (labels[j] == li) && (j != i);
        if (is_pos) s_posd[j & (SPC - 1)] = dist;
        score[it] = dist + (is_pos ? 1e6f : 0.f);
    }
    __syncthreads();
    for (int r = 0; r < KRET; ++r) {
        u64 best = ~0ull;
#pragma unroll
        for (int it = 0; it < 16; ++it) {
            u64 p = ((u64)__float_as_uint(score[it]) << 32) | (unsigned)(it * 256 + tid);
            best = best < p ? best : p;
        }
        for (int off = 32; off > 0; off >>= 1) {
            u64 o = __shfl_down(best, off, 64);
            best = best < o ? best : o;
        }
        if ((tid & 63) == 0) s_red[tid >> 6] = best;
        __syncthreads();
        if (tid == 0) {
            u64 w2 = s_red[0];
            w2 = w2 < s_red[1] ? w2 : s_red[1];
            w2 = w2 < s_red[2] ? w2 : s_red[2];
            w2 = w2 < s_red[3] ? w2 : s_red[3];
            s_win = w2;
        }
        __syncthreads();
        u64 w2 = s_win;
        int cj = (int)(w2 & 0xffffffffu);
        if (tid == (cj & 255)) score[cj >> 8] = 1e30f;
        if (tid == 0) { s_negidx[r] = cj; s_negd[r] = __uint_as_float((unsigned)(w2 >> 32)); }
        __syncthreads();
    }
    if (tid == 0) {
        for (int a = 1; a < KRET; ++a) {
            int ix = s_negidx[a]; float dv = s_negd[a];
            int b = a - 1;
            while (b >= 0 && s_negidx[b] > ix) {
                s_negidx[b + 1] = s_negidx[b]; s_negd[b + 1] = s_negd[b]; --b;
            }
            s_negidx[b + 1] = ix; s_negd[b + 1] = dv;
        }
    }
    __syncthreads();
    {
        int wave = tid >> 6, lane = tid & 63;
        int gb = i & ~(SPC - 1);
        for (int p = wave; p < 2 * KRET; p += 4) {
            int tgt;
            if (p < KRET) {
                int k = p;
                int m = k + (k >= (i & (SPC - 1)) ? 1 : 0);
                tgt = gb + m;
            } else tgt = s_negidx[p - KRET];
            float d0 = emb[(size_t)tgt * D + lane] - s_anchor[lane];
            float d1 = emb[(size_t)tgt * D + 64 + lane] - s_anchor[64 + lane];
            float s = d0 * d0 + d1 * d1;
            for (int off = 32; off > 0; off >>= 1) s += __shfl_down(s, off, 64);
            if (lane == 0) s_dreal[p] = sqrtf(s + 1e-8f);
        }
    }
    __syncthreads();
    if (tid == 0) {
        float ls = 0.f, cnt = 0.f;
        for (int k = 0; k < KRET; ++k) {
            int m = k + (k >= (i & (SPC - 1)) ? 1 : 0);
            if (s_posd[m] < s_negd[k] + MARGIN) {
                ls += (s_dreal[k] + MARGIN) + fmaxf(MARGIN - s_dreal[KRET + k], 0.f);
                cnt += 1.f;
            }
        }
        if (ls != 0.f) atomicAdd(&ws_acc[0], ls);
        if (cnt != 0.f) atomicAdd(&ws_acc[1], cnt);
    }
}

__global__ void finalize_kernel(const float* __restrict__ ws_acc, float* __restrict__ out) {
    float ls = ws_acc[0], cnt = ws_acc[1];
    out[0] = cnt > 0.f ? ls / cnt : ls;
}

extern "C" void kernel_launch(void* const* d_in, const int* in_sizes, int n_in,
                              void* d_out, int out_size, void* d_ws, size_t ws_size,
                              hipStream_t stream) {
    const float* emb     = (const float*)d_in[0];
    const int*   labels  = (const int*)d_in[1];
    const float* emb1    = (const float*)d_in[2];
    const int*   labels1 = (const int*)d_in[3];
    float* ws = (float*)d_ws;

    hipMemsetAsync(d_ws, 0, 2 * sizeof(float), stream);

    const size_t need = ((size_t)1089536 + (size_t)NROWS * CPR * 2) * sizeof(float);
    if (ws_size >= need) {
        float*  diag  = ws + 4096;
        float*  posd  = ws + 8192;
        ushort* embH  = (ushort*)(ws + 40960);
        ushort* embL  = (ushort*)(ws + 303104);
        ushort* emb1H = (ushort*)(ws + 565248);
        ushort* emb1L = (ushort*)(ws + 827392);
        u64*    cand  = (u64*)(ws + 1089536);

        prep_kernel<<<NROWS / 4, 256, 0, stream>>>(emb, emb1, embH, embL, emb1H, emb1L, diag);
        dim3 grid(NROWS / 128, NROWS / 128);
        dist_mfma<<<grid, 256, 0, stream>>>(embH, embL, emb1H, emb1L, labels, labels1, diag, posd, cand);
        merge_kernel<<<NROWS / 4, 256, 0, stream>>>(emb, posd, cand, ws);
        finalize_kernel<<<1, 1, 0, stream>>>(ws, (float*)d_out);
    } else {
        float* diag = ws + 2;
        diag_kernel<<<NROWS / 4, 256, 0, stream>>>(emb, emb1, diag);
        main_kernel<<<NROWS, 256, 0, stream>>>(emb, emb1, labels, labels1, diag, ws);
        finalize_kernel<<<1, 1, 0, stream>>>(ws, (float*)d_out);
    }
}

// Round 5
// 87.329 us; speedup vs baseline: 2.5909x; 2.1267x over previous
//
#include <hip/hip_runtime.h>
#include <math.h>

#define NROWS 4096
#define D 128
#define SPC 8
#define KRET 7
#define MARGIN 0.2f
#define NTILE 32              // 4096/128 column tiles
#define CPT 14                // candidates per (row, tile): 2 halves x top-7
#define CPR (NTILE * CPT)     // 448 candidates per row

typedef unsigned long long u64;
typedef __attribute__((ext_vector_type(8))) short short8;   // 8 bf16 (4 VGPRs)
typedef __attribute__((ext_vector_type(4))) float f32x4;    // MFMA accumulator

__device__ __forceinline__ u64 minu(u64 a, u64 b) { return a < b ? a : b; }

// bf16 round-to-nearest-even split helpers (bit-exact, header-independent)
__device__ __forceinline__ ushort f2bf_rne(float x) {
    unsigned u = __float_as_uint(x);
    unsigned r = (u + 0x7fffu + ((u >> 16) & 1u)) >> 16;
    return (ushort)r;
}
__device__ __forceinline__ float bf2f(ushort h) {
    return __uint_as_float((unsigned)h << 16);
}

// ws layout (floats):
//   [0..1]              (fallback accums only)
//   [4096 .. 8191]      diag
//   [8192 .. 40959]     posd (4096 x 8 f32)
//   [40960 .. ]         embH (4096x128 ushort = 262144 f)
//   [303104 .. ]        embL
//   [565248 .. ]        emb1H
//   [827392 .. ]        emb1L
//   [1089536 .. ]       cand (u64, 4096 x 448) = 3670016 floats
//   [4759552 .. ]       rowls (4096 f32)
//   [4763648 .. ]       rowcnt (4096 f32)
// Fallback path: [0],[1] accum, [2..2+NROWS) diag.

// ---- prep: bf16 hi/lo split of both matrices + Gram diagonal ----
__global__ __launch_bounds__(256) void prep_kernel(const float* __restrict__ emb,
                                                   const float* __restrict__ emb1,
                                                   ushort* __restrict__ embH, ushort* __restrict__ embL,
                                                   ushort* __restrict__ emb1H, ushort* __restrict__ emb1L,
                                                   float* __restrict__ diag) {
    const int lane = threadIdx.x & 63;
    const int row = blockIdx.x * 4 + (threadIdx.x >> 6);
    const size_t base = (size_t)row * D + 2 * lane;
    const float2 a = *(const float2*)(emb + base);
    const float2 b = *(const float2*)(emb1 + base);

    ushort ah0 = f2bf_rne(a.x), ah1 = f2bf_rne(a.y);
    ushort al0 = f2bf_rne(a.x - bf2f(ah0)), al1 = f2bf_rne(a.y - bf2f(ah1));
    ushort bh0 = f2bf_rne(b.x), bh1 = f2bf_rne(b.y);
    ushort bl0 = f2bf_rne(b.x - bf2f(bh0)), bl1 = f2bf_rne(b.y - bf2f(bh1));

    *(ushort2*)(embH + base)  = make_ushort2(ah0, ah1);
    *(ushort2*)(embL + base)  = make_ushort2(al0, al1);
    *(ushort2*)(emb1H + base) = make_ushort2(bh0, bh1);
    *(ushort2*)(emb1L + base) = make_ushort2(bl0, bl1);

    float s = a.x * b.x + a.y * b.y;
#pragma unroll
    for (int off = 1; off < 64; off <<= 1) s += __shfl_xor(s, off, 64);
    if (lane == 0) diag[row] = s;
}

// ---- dist tile via 3-term bf16-split MFMA + fused per-tile top-7 ----
// 128x128 tile, 4 waves, each wave 64x64 output via 16x16x32 MFMAs.
// LDS tiles [128][72] bf16 (pad 72 -> stride 144B, bank-quad stride 9 == 1 mod 8: conflict-free).
__global__ __launch_bounds__(256, 2) void dist_mfma(const ushort* __restrict__ embH, const ushort* __restrict__ embL,
                                                    const ushort* __restrict__ emb1H, const ushort* __restrict__ emb1L,
                                                    const int* __restrict__ labels, const int* __restrict__ labels1,
                                                    const float* __restrict__ diag,
                                                    float* __restrict__ posd, u64* __restrict__ cand) {
    __shared__ ushort smem[36864];        // 73728 B: AH|AL|BH|BL [128][72] bf16 each
    __shared__ float sdA[128], sdB[128];
    __shared__ int sLi[128], sLj[128];
    ushort* AH = smem;
    ushort* AL = smem + 9216;
    ushort* BH = smem + 18432;
    ushort* BL = smem + 27648;
    float* distbuf = (float*)(void*)smem;  // [128][132] f32 (67584 B), overlays staging after k-loop

    const int t = threadIdx.x;
    const int i0 = blockIdx.y * 128, j0 = blockIdx.x * 128;

    if (t < 128) { sdA[t] = diag[i0 + t]; sLi[t] = labels1[i0 + t]; }
    else         { sdB[t - 128] = diag[j0 + t - 128]; sLj[t - 128] = labels[j0 + t - 128]; }

    const int w = t >> 6, l = t & 63;
    const int R = (w >> 1) * 64, C = (w & 1) * 64;
    const int lr = l & 15, lg = l >> 4;

    f32x4 acc[4][4];
#pragma unroll
    for (int m = 0; m < 4; ++m)
#pragma unroll
        for (int n = 0; n < 4; ++n) acc[m][n] = (f32x4){0.f, 0.f, 0.f, 0.f};

    const int srow = t & 127;              // staging row
    for (int p = 0; p < 2; ++p) {
        if (p) __syncthreads();            // phase-0 LDS reads complete before restage
#pragma unroll
        for (int n = 0; n < 4; ++n) {
            const int c = n * 2 + (t >> 7);                         // 0..7
            const size_t gA = (size_t)(i0 + srow) * D + p * 64 + c * 8;
            const size_t gB = (size_t)(j0 + srow) * D + p * 64 + c * 8;
            const int ld = srow * 72 + c * 8;
            *(uint4*)(AH + ld) = *(const uint4*)(embH + gA);
            *(uint4*)(AL + ld) = *(const uint4*)(embL + gA);
            *(uint4*)(BH + ld) = *(const uint4*)(emb1H + gB);
            *(uint4*)(BL + ld) = *(const uint4*)(emb1L + gB);
        }
        __syncthreads();

#pragma unroll
        for (int ks = 0; ks < 2; ++ks) {
            const int koff = ks * 32 + lg * 8;
            short8 ah[4], al4[4], bh[4], bl4[4];
#pragma unroll
            for (int m = 0; m < 4; ++m) {
                const int ra = (R + 16 * m + lr) * 72 + koff;
                ah[m]  = *(const short8*)(AH + ra);
                al4[m] = *(const short8*)(AL + ra);
                const int rb = (C + 16 * m + lr) * 72 + koff;
                bh[m]  = *(const short8*)(BH + rb);
                bl4[m] = *(const short8*)(BL + rb);
            }
#pragma unroll
            for (int m = 0; m < 4; ++m)
#pragma unroll
                for (int n = 0; n < 4; ++n) {
                    acc[m][n] = __builtin_amdgcn_mfma_f32_16x16x32_bf16(ah[m],  bh[n],  acc[m][n], 0, 0, 0);
                    acc[m][n] = __builtin_amdgcn_mfma_f32_16x16x32_bf16(ah[m],  bl4[n], acc[m][n], 0, 0, 0);
                    acc[m][n] = __builtin_amdgcn_mfma_f32_16x16x32_bf16(al4[m], bh[n],  acc[m][n], 0, 0, 0);
                }
        }
    }
    __syncthreads();   // all LDS frag reads done; staging area becomes distbuf

    // epilogue: scores -> distbuf, posd capture.
    // C/D layout (m89-verified): col = lane&15, row = (lane>>4)*4 + reg
#pragma unroll
    for (int m = 0; m < 4; ++m)
#pragma unroll
        for (int n = 0; n < 4; ++n)
#pragma unroll
            for (int r = 0; r < 4; ++r) {
                const int row = R + 16 * m + 4 * lg + r;
                const int col = C + 16 * n + lr;
                const float v = acc[m][n][r];
                const float dist = sqrtf(fmaxf(sdA[row] + sdB[col] - 2.f * v, 1e-4f));
                const int gi = i0 + row, gj = j0 + col;
                const bool pos = (sLj[col] == sLi[row]) && (gi != gj);
                if (pos) posd[(size_t)gi * SPC + (gj & (SPC - 1))] = dist;
                distbuf[row * 132 + col] = dist + (pos ? 1e6f : 0.f);
            }
    __syncthreads();

    // selection: 2 threads per row, register insertion-scan of 64 scores each
    {
        const int row = t >> 1, h = t & 1;
        u64 s[KRET];
#pragma unroll
        for (int k = 0; k < KRET; ++k) s[k] = ~0ull;
        const float* dr = distbuf + row * 132 + 64 * h;
        for (int c = 0; c < 64; ++c) {
            const int cc = (c + row) & 63;            // diagonal stagger: conflict-free reads
            const float v = dr[cc];
            const u64 pk = ((u64)__float_as_uint(v) << 32) | (unsigned)(j0 + 64 * h + cc);
            if (pk < s[KRET - 1]) {
                u64 tmp = pk;
#pragma unroll
                for (int k = 0; k < KRET; ++k) {
                    const u64 lo = minu(s[k], tmp);
                    tmp = s[k] ^ tmp ^ lo;
                    s[k] = lo;
                }
            }
        }
        u64* cw = cand + (size_t)(i0 + row) * CPR + (j0 >> 7) * CPT + h * KRET;
#pragma unroll
        for (int k = 0; k < KRET; ++k) cw[k] = s[k];
    }
}

// ---- merge 448 candidates/row -> global top-7, validity, loss. Wave per row. ----
// No global atomics: per-row (ls, cnt) partials, reduced deterministically in finalize.
__global__ __launch_bounds__(256) void merge_kernel(const float* __restrict__ emb,
                                                    const float* __restrict__ posd,
                                                    const u64* __restrict__ cand,
                                                    float* __restrict__ rowls,
                                                    float* __restrict__ rowcnt) {
    const int lane = threadIdx.x & 63;
    const int i = blockIdx.x * 4 + (threadIdx.x >> 6);
    const u64* cr = cand + (size_t)i * CPR;
    u64 e[7];
#pragma unroll
    for (int q = 0; q < 7; ++q) e[q] = cr[q * 64 + lane];

    u64 w[KRET];
#pragma unroll
    for (int r = 0; r < KRET; ++r) {
        u64 m = e[0];
#pragma unroll
        for (int q = 1; q < 7; ++q) m = minu(m, e[q]);
#pragma unroll
        for (int off = 1; off < 64; off <<= 1) m = minu(m, __shfl_xor(m, off, 64));
        w[r] = m;
#pragma unroll
        for (int q = 0; q < 7; ++q) e[q] = (e[q] == m) ? ~0ull : e[q];
    }

    // sort winners by column index: repack (idx<<32)|distbits, Batcher-8
    u64 s[8];
#pragma unroll
    for (int r = 0; r < KRET; ++r) s[r] = (w[r] << 32) | (w[r] >> 32);
    s[7] = ~0ull;
#define CE(x, y) { u64 lo = minu(s[x], s[y]); u64 hi = s[x] ^ s[y] ^ lo; s[x] = lo; s[y] = hi; }
    CE(0,1) CE(2,3) CE(4,5) CE(6,7)
    CE(0,2) CE(1,3) CE(4,6) CE(5,7)
    CE(1,2) CE(5,6)
    CE(0,4) CE(1,5) CE(2,6) CE(3,7)
    CE(2,4) CE(3,5)
    CE(1,2) CE(3,4) CE(5,6)
#undef CE

    const int ig = i & (SPC - 1);
    float ls = 0.f, cnt = 0.f;
    bool any = false;
    bool v[KRET];
    int nidx[KRET];
#pragma unroll
    for (int k = 0; k < KRET; ++k) {
        nidx[k] = (int)(s[k] >> 32);
        const float dneg = __uint_as_float((unsigned)(s[k] & 0xffffffffu));
        const int m = k + (k >= ig ? 1 : 0);
        const float dp = posd[(size_t)i * SPC + m];
        v[k] = dp < dneg + MARGIN;       // wave-uniform
        any = any || v[k];
    }

    if (any) {
        const float a0 = emb[(size_t)i * D + lane];
        const float a1 = emb[(size_t)i * D + 64 + lane];
#pragma unroll
        for (int k = 0; k < KRET; ++k) {
            if (v[k]) {
                const int m = k + (k >= ig ? 1 : 0);
                const int tp = (i & ~(SPC - 1)) + m;
                const int tn = nidx[k];
                float d0 = emb[(size_t)tp * D + lane] - a0;
                float d1 = emb[(size_t)tp * D + 64 + lane] - a1;
                float sp = d0 * d0 + d1 * d1;
                float g0 = emb[(size_t)tn * D + lane] - a0;
                float g1 = emb[(size_t)tn * D + 64 + lane] - a1;
                float sn = g0 * g0 + g1 * g1;
#pragma unroll
                for (int off = 1; off < 64; off <<= 1) {
                    sp += __shfl_xor(sp, off, 64);
                    sn += __shfl_xor(sn, off, 64);
                }
                ls += (sqrtf(sp + 1e-8f) + MARGIN) + fmaxf(MARGIN - sqrtf(sn + 1e-8f), 0.f);
                cnt += 1.f;
            }
        }
    }
    if (lane == 0) {           // always write: poison-safe, deterministic
        rowls[i] = ls;
        rowcnt[i] = cnt;
    }
}

// ---- deterministic single-block reduction over 4096 per-row partials ----
__global__ __launch_bounds__(256) void finalize_kernel(const float* __restrict__ rowls,
                                                       const float* __restrict__ rowcnt,
                                                       float* __restrict__ out) {
    const int t = threadIdx.x;
    __shared__ float sls[4], scnt[4];
    float ls = 0.f, cnt = 0.f;
#pragma unroll
    for (int q = 0; q < NROWS / 256; ++q) {
        ls += rowls[q * 256 + t];
        cnt += rowcnt[q * 256 + t];
    }
#pragma unroll
    for (int off = 1; off < 64; off <<= 1) {
        ls += __shfl_xor(ls, off, 64);
        cnt += __shfl_xor(cnt, off, 64);
    }
    if ((t & 63) == 0) { sls[t >> 6] = ls; scnt[t >> 6] = cnt; }
    __syncthreads();
    if (t == 0) {
        float L = sls[0] + sls[1] + sls[2] + sls[3];
        float C = scnt[0] + scnt[1] + scnt[2] + scnt[3];
        out[0] = C > 0.f ? L / C : L;
    }
}

// ---------------- Fallback path (round-1, only if ws too small) ----------------
__global__ __launch_bounds__(256) void diag_kernel(const float* __restrict__ emb,
                                                   const float* __restrict__ emb1,
                                                   float* __restrict__ diag) {
    int wave = threadIdx.x >> 6;
    int lane = threadIdx.x & 63;
    int row = blockIdx.x * 4 + wave;
    const float* a = emb + (size_t)row * D;
    const float* b = emb1 + (size_t)row * D;
    float s = a[lane] * b[lane] + a[lane + 64] * b[lane + 64];
    for (int off = 32; off > 0; off >>= 1) s += __shfl_down(s, off, 64);
    if (lane == 0) diag[row] = s;
}

__global__ __launch_bounds__(256) void main_kernel(const float* __restrict__ emb,
                                                   const float* __restrict__ emb1,
                                                   const int* __restrict__ labels,
                                                   const int* __restrict__ labels1,
                                                   const float* __restrict__ diag,
                                                   float* __restrict__ ws_acc) {
    const int i = blockIdx.x;
    const int tid = threadIdx.x;
    __shared__ float s_anchor[D];
    __shared__ float s_posd[SPC];
    __shared__ u64 s_red[4];
    __shared__ u64 s_win;
    __shared__ int s_negidx[KRET];
    __shared__ float s_negd[KRET];
    __shared__ float s_dreal[2 * KRET];

    if (tid < D) s_anchor[tid] = emb[(size_t)i * D + tid];
    __syncthreads();
    const float diag_i = diag[i];
    const int li = labels1[i];
    float score[16];
#pragma unroll
    for (int it = 0; it < 16; ++it) {
        int j = it * 256 + tid;
        const float4* r = (const float4*)(emb1 + (size_t)j * D);
        float acc = 0.f;
#pragma unroll
        for (int q = 0; q < D / 4; ++q) {
            float4 vv = r[q];
            acc = fmaf(vv.x, s_anchor[4 * q + 0], acc);
            acc = fmaf(vv.y, s_anchor[4 * q + 1], acc);
            acc = fmaf(vv.z, s_anchor[4 * q + 2], acc);
            acc = fmaf(vv.w, s_anchor[4 * q + 3], acc);
        }
        float d2 = diag_i + diag[j] - 2.f * acc;
        float dist = sqrtf(fmaxf(d2, 1e-4f));
        bool is_pos = (labels[j] == li) && (j != i);
        if (is_pos) s_posd[j & (SPC - 1)] = dist;
        score[it] = dist + (is_pos ? 1e6f : 0.f);
    }
    __syncthreads();
    for (int r = 0; r < KRET; ++r) {
        u64 best = ~0ull;
#pragma unroll
        for (int it = 0; it < 16; ++it) {
            u64 p = ((u64)__float_as_uint(score[it]) << 32) | (unsigned)(it * 256 + tid);
            best = best < p ? best : p;
        }
        for (int off = 32; off > 0; off >>= 1) {
            u64 o = __shfl_down(best, off, 64);
            best = best < o ? best : o;
        }
        if ((tid & 63) == 0) s_red[tid >> 6] = best;
        __syncthreads();
        if (tid == 0) {
            u64 w2 = s_red[0];
            w2 = w2 < s_red[1] ? w2 : s_red[1];
            w2 = w2 < s_red[2] ? w2 : s_red[2];
            w2 = w2 < s_red[3] ? w2 : s_red[3];
            s_win = w2;
        }
        __syncthreads();
        u64 w2 = s_win;
        int cj = (int)(w2 & 0xffffffffu);
        if (tid == (cj & 255)) score[cj >> 8] = 1e30f;
        if (tid == 0) { s_negidx[r] = cj; s_negd[r] = __uint_as_float((unsigned)(w2 >> 32)); }
        __syncthreads();
    }
    if (tid == 0) {
        for (int a = 1; a < KRET; ++a) {
            int ix = s_negidx[a]; float dv = s_negd[a];
            int b = a - 1;
            while (b >= 0 && s_negidx[b] > ix) {
                s_negidx[b + 1] = s_negidx[b]; s_negd[b + 1] = s_negd[b]; --b;
            }
            s_negidx[b + 1] = ix; s_negd[b + 1] = dv;
        }
    }
    __syncthreads();
    {
        int wave = tid >> 6, lane = tid & 63;
        int gb = i & ~(SPC - 1);
        for (int p = wave; p < 2 * KRET; p += 4) {
            int tgt;
            if (p < KRET) {
                int k = p;
                int m = k + (k >= (i & (SPC - 1)) ? 1 : 0);
                tgt = gb + m;
            } else tgt = s_negidx[p - KRET];
            float d0 = emb[(size_t)tgt * D + lane] - s_anchor[lane];
            float d1 = emb[(size_t)tgt * D + 64 + lane] - s_anchor[64 + lane];
            float s = d0 * d0 + d1 * d1;
            for (int off = 32; off > 0; off >>= 1) s += __shfl_down(s, off, 64);
            if (lane == 0) s_dreal[p] = sqrtf(s + 1e-8f);
        }
    }
    __syncthreads();
    if (tid == 0) {
        float ls = 0.f, cnt = 0.f;
        for (int k = 0; k < KRET; ++k) {
            int m = k + (k >= (i & (SPC - 1)) ? 1 : 0);
            if (s_posd[m] < s_negd[k] + MARGIN) {
                ls += (s_dreal[k] + MARGIN) + fmaxf(MARGIN - s_dreal[KRET + k], 0.f);
                cnt += 1.f;
            }
        }
        if (ls != 0.f) atomicAdd(&ws_acc[0], ls);
        if (cnt != 0.f) atomicAdd(&ws_acc[1], cnt);
    }
}

__global__ void finalize_ws(const float* __restrict__ ws_acc, float* __restrict__ out) {
    float ls = ws_acc[0], cnt = ws_acc[1];
    out[0] = cnt > 0.f ? ls / cnt : ls;
}

extern "C" void kernel_launch(void* const* d_in, const int* in_sizes, int n_in,
                              void* d_out, int out_size, void* d_ws, size_t ws_size,
                              hipStream_t stream) {
    const float* emb     = (const float*)d_in[0];
    const int*   labels  = (const int*)d_in[1];
    const float* emb1    = (const float*)d_in[2];
    const int*   labels1 = (const int*)d_in[3];
    float* ws = (float*)d_ws;

    const size_t need = ((size_t)4763648 + NROWS) * sizeof(float);
    if (ws_size >= need) {
        float*  diag   = ws + 4096;
        float*  posd   = ws + 8192;
        ushort* embH   = (ushort*)(ws + 40960);
        ushort* embL   = (ushort*)(ws + 303104);
        ushort* emb1H  = (ushort*)(ws + 565248);
        ushort* emb1L  = (ushort*)(ws + 827392);
        u64*    cand   = (u64*)(ws + 1089536);
        float*  rowls  = ws + 4759552;
        float*  rowcnt = ws + 4763648;

        prep_kernel<<<NROWS / 4, 256, 0, stream>>>(emb, emb1, embH, embL, emb1H, emb1L, diag);
        dim3 grid(NROWS / 128, NROWS / 128);
        dist_mfma<<<grid, 256, 0, stream>>>(embH, embL, emb1H, emb1L, labels, labels1, diag, posd, cand);
        merge_kernel<<<NROWS / 4, 256, 0, stream>>>(emb, posd, cand, rowls, rowcnt);
        finalize_kernel<<<1, 256, 0, stream>>>(rowls, rowcnt, (float*)d_out);
    } else {
        hipMemsetAsync(d_ws, 0, 2 * sizeof(float), stream);
        float* diag = ws + 2;
        diag_kernel<<<NROWS / 4, 256, 0, stream>>>(emb, emb1, diag);
        main_kernel<<<NROWS, 256, 0, stream>>>(emb, emb1, labels, labels1, diag, ws);
        finalize_ws<<<1, 1, 0, stream>>>(ws, (float*)d_out);
    }
}

// Round 6
// 71.150 us; speedup vs baseline: 3.1801x; 1.2274x over previous
//
#include <hip/hip_runtime.h>
#include <math.h>

#define NROWS 4096
#define D 128
#define SPC 8
#define KRET 7
#define MARGIN 0.2f
#define NTILE 32              // 4096/128 column tiles
#define CPT 14                // candidates per (row, tile): 2 halves x top-7
#define CPR (NTILE * CPT)     // 448 candidates per row

typedef unsigned long long u64;
typedef __attribute__((ext_vector_type(8))) short short8;   // 8 bf16 (4 VGPRs)
typedef __attribute__((ext_vector_type(4))) float f32x4;    // MFMA accumulator

__device__ __forceinline__ u64 minu(u64 a, u64 b) { return a < b ? a : b; }

// bf16 round-to-nearest-even helpers
__device__ __forceinline__ ushort f2bf_rne(float x) {
    unsigned u = __float_as_uint(x);
    unsigned r = (u + 0x7fffu + ((u >> 16) & 1u)) >> 16;
    return (ushort)r;
}

// ws layout (floats):
//   [0..1]               (fallback accums only)
//   [4096 .. 8191]       diag
//   [8192 .. 40959]      posd (4096 x 8 f32)
//   [40960 .. 106495]    embH  (4096x128 bf16)
//   [106496 .. 172031]   emb1H (4096x128 bf16)
//   [172032 .. 3842047]  cand (u64, 4096 x 448)
//   [3842048 ..]         rowls (4096), rowcnt (4096)
// Fallback path: [0],[1] accum, [2..2+NROWS) diag.

// ---- prep: bf16 round of both matrices + exact f32 Gram diagonal ----
__global__ __launch_bounds__(256) void prep_kernel(const float* __restrict__ emb,
                                                   const float* __restrict__ emb1,
                                                   ushort* __restrict__ embH,
                                                   ushort* __restrict__ emb1H,
                                                   float* __restrict__ diag) {
    const int lane = threadIdx.x & 63;
    const int row = blockIdx.x * 4 + (threadIdx.x >> 6);
    const size_t base = (size_t)row * D + 2 * lane;
    const float2 a = *(const float2*)(emb + base);
    const float2 b = *(const float2*)(emb1 + base);

    *(ushort2*)(embH + base)  = make_ushort2(f2bf_rne(a.x), f2bf_rne(a.y));
    *(ushort2*)(emb1H + base) = make_ushort2(f2bf_rne(b.x), f2bf_rne(b.y));

    float s = a.x * b.x + a.y * b.y;
#pragma unroll
    for (int off = 1; off < 64; off <<= 1) s += __shfl_xor(s, off, 64);
    if (lane == 0) diag[row] = s;
}

// ---- dist tile via bf16 MFMA + fused per-tile top-7 ----
// 128x128 tile, 4 waves, each wave owns a 64x64 quadrant (R,C).
// LDS: AH|BH [128][72] bf16 (36.9 KB) overlaid by bf16 score buf [128][132] (33.8 KB)
// -> ~39 KB total -> 4 blocks/CU.
__global__ __launch_bounds__(256, 4) void dist_mfma(const ushort* __restrict__ embH,
                                                    const ushort* __restrict__ emb1H,
                                                    const int* __restrict__ labels,
                                                    const int* __restrict__ labels1,
                                                    const float* __restrict__ diag,
                                                    float* __restrict__ posd, u64* __restrict__ cand) {
    __shared__ ushort smem[2][9216];      // AH, BH: [128][72] bf16 each
    __shared__ float sdA[128], sdB[128];
    __shared__ int sLi[128], sLj[128];
    ushort* AH = smem[0];
    ushort* BH = smem[1];
    ushort* distbuf = (ushort*)(void*)smem;   // [128][132] bf16 scores, overlays staging

    const int t = threadIdx.x;
    const int i0 = blockIdx.y * 128, j0 = blockIdx.x * 128;

    if (t < 128) { sdA[t] = diag[i0 + t]; sLi[t] = labels1[i0 + t]; }
    else         { sdB[t - 128] = diag[j0 + t - 128]; sLj[t - 128] = labels[j0 + t - 128]; }

    const int w = t >> 6, l = t & 63;
    const int R = (w >> 1) * 64, C = (w & 1) * 64;
    const int lr = l & 15, lg = l >> 4;

    f32x4 acc[4][4];
#pragma unroll
    for (int m = 0; m < 4; ++m)
#pragma unroll
        for (int n = 0; n < 4; ++n) acc[m][n] = (f32x4){0.f, 0.f, 0.f, 0.f};

    const int srow = t & 127;
    for (int p = 0; p < 2; ++p) {
        if (p) __syncthreads();            // phase-0 frag reads complete before restage
#pragma unroll
        for (int n = 0; n < 4; ++n) {
            const int c = n * 2 + (t >> 7);                         // 0..7
            const size_t gA = (size_t)(i0 + srow) * D + p * 64 + c * 8;
            const size_t gB = (size_t)(j0 + srow) * D + p * 64 + c * 8;
            const int ld = srow * 72 + c * 8;
            *(uint4*)(AH + ld) = *(const uint4*)(embH + gA);
            *(uint4*)(BH + ld) = *(const uint4*)(emb1H + gB);
        }
        __syncthreads();

#pragma unroll
        for (int ks = 0; ks < 2; ++ks) {
            const int koff = ks * 32 + lg * 8;
            short8 ah[4], bh[4];
#pragma unroll
            for (int m = 0; m < 4; ++m) {
                ah[m] = *(const short8*)(AH + (R + 16 * m + lr) * 72 + koff);
                bh[m] = *(const short8*)(BH + (C + 16 * m + lr) * 72 + koff);
            }
#pragma unroll
            for (int m = 0; m < 4; ++m)
#pragma unroll
                for (int n = 0; n < 4; ++n)
                    acc[m][n] = __builtin_amdgcn_mfma_f32_16x16x32_bf16(ah[m], bh[n], acc[m][n], 0, 0, 0);
        }
    }
    __syncthreads();   // all waves' frag reads done; staging area becomes score buf

    // epilogue: bf16 scores -> distbuf, posd capture (f32 dist).
    // C/D layout (m89-verified): col = lane&15, row = (lane>>4)*4 + reg
#pragma unroll
    for (int m = 0; m < 4; ++m)
#pragma unroll
        for (int n = 0; n < 4; ++n)
#pragma unroll
            for (int r = 0; r < 4; ++r) {
                const int row = R + 16 * m + 4 * lg + r;
                const int col = C + 16 * n + lr;
                const float dist = sqrtf(fmaxf(sdA[row] + sdB[col] - 2.f * acc[m][n][r], 1e-4f));
                const int gi = i0 + row, gj = j0 + col;
                const bool pos = (sLj[col] == sLi[row]) && (gi != gj);
                if (pos) posd[(size_t)gi * SPC + (gj & (SPC - 1))] = dist;
                distbuf[row * 132 + col] = f2bf_rne(dist + (pos ? 1e6f : 0.f));
            }

    // wave-local sync: this wave's score writes cover exactly the quadrant it scans
    asm volatile("s_waitcnt lgkmcnt(0)" ::: "memory");

    // selection: 1 thread per row over this wave's 64 cols (register insertion-scan)
    {
        const int row = R + l;
        u64 s[KRET];
#pragma unroll
        for (int k = 0; k < KRET; ++k) s[k] = ~0ull;
        const ushort* dr = distbuf + row * 132 + C;
#pragma unroll 4
        for (int c = 0; c < 64; ++c) {
            const int cc = (c + row) & 63;            // diagonal stagger
            const unsigned fb = ((unsigned)dr[cc]) << 16;
            const u64 pk = ((u64)fb << 32) | (unsigned)(j0 + C + cc);
            if (pk < s[KRET - 1]) {
                u64 tmp = pk;
#pragma unroll
                for (int k = 0; k < KRET; ++k) {
                    const u64 lo = minu(s[k], tmp);
                    tmp = s[k] ^ tmp ^ lo;
                    s[k] = lo;
                }
            }
        }
        u64* cw = cand + (size_t)(i0 + row) * CPR + (j0 >> 7) * CPT + (C >> 6) * KRET;
#pragma unroll
        for (int k = 0; k < KRET; ++k) cw[k] = s[k];
    }
}

// ---- merge 448 candidates/row -> global top-7, validity, loss. Wave per row. ----
__global__ __launch_bounds__(256) void merge_kernel(const float* __restrict__ emb,
                                                    const float* __restrict__ posd,
                                                    const u64* __restrict__ cand,
                                                    float* __restrict__ rowls,
                                                    float* __restrict__ rowcnt) {
    const int lane = threadIdx.x & 63;
    const int i = blockIdx.x * 4 + (threadIdx.x >> 6);
    const u64* cr = cand + (size_t)i * CPR;
    u64 e[7];
#pragma unroll
    for (int q = 0; q < 7; ++q) e[q] = cr[q * 64 + lane];

    u64 w[KRET];
#pragma unroll
    for (int r = 0; r < KRET; ++r) {
        u64 m = e[0];
#pragma unroll
        for (int q = 1; q < 7; ++q) m = minu(m, e[q]);
#pragma unroll
        for (int off = 1; off < 64; off <<= 1) m = minu(m, __shfl_xor(m, off, 64));
        w[r] = m;
#pragma unroll
        for (int q = 0; q < 7; ++q) e[q] = (e[q] == m) ? ~0ull : e[q];
    }

    // sort winners by column index: repack (idx<<32)|distbits, Batcher-8
    u64 s[8];
#pragma unroll
    for (int r = 0; r < KRET; ++r) s[r] = (w[r] << 32) | (w[r] >> 32);
    s[7] = ~0ull;
#define CE(x, y) { u64 lo = minu(s[x], s[y]); u64 hi = s[x] ^ s[y] ^ lo; s[x] = lo; s[y] = hi; }
    CE(0,1) CE(2,3) CE(4,5) CE(6,7)
    CE(0,2) CE(1,3) CE(4,6) CE(5,7)
    CE(1,2) CE(5,6)
    CE(0,4) CE(1,5) CE(2,6) CE(3,7)
    CE(2,4) CE(3,5)
    CE(1,2) CE(3,4) CE(5,6)
#undef CE

    const int ig = i & (SPC - 1);
    float ls = 0.f, cnt = 0.f;
    bool any = false;
    bool v[KRET];
    int nidx[KRET];
#pragma unroll
    for (int k = 0; k < KRET; ++k) {
        nidx[k] = (int)(s[k] >> 32);
        const float dneg = __uint_as_float((unsigned)(s[k] & 0xffffffffu));
        const int m = k + (k >= ig ? 1 : 0);
        const float dp = posd[(size_t)i * SPC + m];
        v[k] = dp < dneg + MARGIN;       // wave-uniform
        any = any || v[k];
    }

    if (any) {
        const float a0 = emb[(size_t)i * D + lane];
        const float a1 = emb[(size_t)i * D + 64 + lane];
#pragma unroll
        for (int k = 0; k < KRET; ++k) {
            if (v[k]) {
                const int m = k + (k >= ig ? 1 : 0);
                const int tp = (i & ~(SPC - 1)) + m;
                const int tn = nidx[k];
                float d0 = emb[(size_t)tp * D + lane] - a0;
                float d1 = emb[(size_t)tp * D + 64 + lane] - a1;
                float sp = d0 * d0 + d1 * d1;
                float g0 = emb[(size_t)tn * D + lane] - a0;
                float g1 = emb[(size_t)tn * D + 64 + lane] - a1;
                float sn = g0 * g0 + g1 * g1;
#pragma unroll
                for (int off = 1; off < 64; off <<= 1) {
                    sp += __shfl_xor(sp, off, 64);
                    sn += __shfl_xor(sn, off, 64);
                }
                ls += (sqrtf(sp + 1e-8f) + MARGIN) + fmaxf(MARGIN - sqrtf(sn + 1e-8f), 0.f);
                cnt += 1.f;
            }
        }
    }
    if (lane == 0) {           // always write: poison-safe, deterministic
        rowls[i] = ls;
        rowcnt[i] = cnt;
    }
}

// ---- deterministic single-block reduction over 4096 per-row partials ----
__global__ __launch_bounds__(256) void finalize_kernel(const float* __restrict__ rowls,
                                                       const float* __restrict__ rowcnt,
                                                       float* __restrict__ out) {
    const int t = threadIdx.x;
    __shared__ float sls[4], scnt[4];
    float ls = 0.f, cnt = 0.f;
#pragma unroll
    for (int q = 0; q < NROWS / 256; ++q) {
        ls += rowls[q * 256 + t];
        cnt += rowcnt[q * 256 + t];
    }
#pragma unroll
    for (int off = 1; off < 64; off <<= 1) {
        ls += __shfl_xor(ls, off, 64);
        cnt += __shfl_xor(cnt, off, 64);
    }
    if ((t & 63) == 0) { sls[t >> 6] = ls; scnt[t >> 6] = cnt; }
    __syncthreads();
    if (t == 0) {
        float L = sls[0] + sls[1] + sls[2] + sls[3];
        float C = scnt[0] + scnt[1] + scnt[2] + scnt[3];
        out[0] = C > 0.f ? L / C : L;
    }
}

// ---------------- Fallback path (round-1, only if ws too small) ----------------
__global__ __launch_bounds__(256) void diag_kernel(const float* __restrict__ emb,
                                                   const float* __restrict__ emb1,
                                                   float* __restrict__ diag) {
    int wave = threadIdx.x >> 6;
    int lane = threadIdx.x & 63;
    int row = blockIdx.x * 4 + wave;
    const float* a = emb + (size_t)row * D;
    const float* b = emb1 + (size_t)row * D;
    float s = a[lane] * b[lane] + a[lane + 64] * b[lane + 64];
    for (int off = 32; off > 0; off >>= 1) s += __shfl_down(s, off, 64);
    if (lane == 0) diag[row] = s;
}

__global__ __launch_bounds__(256) void main_kernel(const float* __restrict__ emb,
                                                   const float* __restrict__ emb1,
                                                   const int* __restrict__ labels,
                                                   const int* __restrict__ labels1,
                                                   const float* __restrict__ diag,
                                                   float* __restrict__ ws_acc) {
    const int i = blockIdx.x;
    const int tid = threadIdx.x;
    __shared__ float s_anchor[D];
    __shared__ float s_posd[SPC];
    __shared__ u64 s_red[4];
    __shared__ u64 s_win;
    __shared__ int s_negidx[KRET];
    __shared__ float s_negd[KRET];
    __shared__ float s_dreal[2 * KRET];

    if (tid < D) s_anchor[tid] = emb[(size_t)i * D + tid];
    __syncthreads();
    const float diag_i = diag[i];
    const int li = labels1[i];
    float score[16];
#pragma unroll
    for (int it = 0; it < 16; ++it) {
        int j = it * 256 + tid;
        const float4* r = (const float4*)(emb1 + (size_t)j * D);
        float acc = 0.f;
#pragma unroll
        for (int q = 0; q < D / 4; ++q) {
            float4 vv = r[q];
            acc = fmaf(vv.x, s_anchor[4 * q + 0], acc);
            acc = fmaf(vv.y, s_anchor[4 * q + 1], acc);
            acc = fmaf(vv.z, s_anchor[4 * q + 2], acc);
            acc = fmaf(vv.w, s_anchor[4 * q + 3], acc);
        }
        float d2 = diag_i + diag[j] - 2.f * acc;
        float dist = sqrtf(fmaxf(d2, 1e-4f));
        bool is_pos = (labels[j] == li) && (j != i);
        if (is_pos) s_posd[j & (SPC - 1)] = dist;
        score[it] = dist + (is_pos ? 1e6f : 0.f);
    }
    __syncthreads();
    for (int r = 0; r < KRET; ++r) {
        u64 best = ~0ull;
#pragma unroll
        for (int it = 0; it < 16; ++it) {
            u64 p = ((u64)__float_as_uint(score[it]) << 32) | (unsigned)(it * 256 + tid);
            best = best < p ? best : p;
        }
        for (int off = 32; off > 0; off >>= 1) {
            u64 o = __shfl_down(best, off, 64);
            best = best < o ? best : o;
        }
        if ((tid & 63) == 0) s_red[tid >> 6] = best;
        __syncthreads();
        if (tid == 0) {
            u64 w2 = s_red[0];
            w2 = w2 < s_red[1] ? w2 : s_red[1];
            w2 = w2 < s_red[2] ? w2 : s_red[2];
            w2 = w2 < s_red[3] ? w2 : s_red[3];
            s_win = w2;
        }
        __syncthreads();
        u64 w2 = s_win;
        int cj = (int)(w2 & 0xffffffffu);
        if (tid == (cj & 255)) score[cj >> 8] = 1e30f;
        if (tid == 0) { s_negidx[r] = cj; s_negd[r] = __uint_as_float((unsigned)(w2 >> 32)); }
        __syncthreads();
    }
    if (tid == 0) {
        for (int a = 1; a < KRET; ++a) {
            int ix = s_negidx[a]; float dv = s_negd[a];
            int b = a - 1;
            while (b >= 0 && s_negidx[b] > ix) {
                s_negidx[b + 1] = s_negidx[b]; s_negd[b + 1] = s_negd[b]; --b;
            }
            s_negidx[b + 1] = ix; s_negd[b + 1] = dv;
        }
    }
    __syncthreads();
    {
        int wave = tid >> 6, lane = tid & 63;
        int gb = i & ~(SPC - 1);
        for (int p = wave; p < 2 * KRET; p += 4) {
            int tgt;
            if (p < KRET) {
                int k = p;
                int m = k + (k >= (i & (SPC - 1)) ? 1 : 0);
                tgt = gb + m;
            } else tgt = s_negidx[p - KRET];
            float d0 = emb[(size_t)tgt * D + lane] - s_anchor[lane];
            float d1 = emb[(size_t)tgt * D + 64 + lane] - s_anchor[64 + lane];
            float s = d0 * d0 + d1 * d1;
            for (int off = 32; off > 0; off >>= 1) s += __shfl_down(s, off, 64);
            if (lane == 0) s_dreal[p] = sqrtf(s + 1e-8f);
        }
    }
    __syncthreads();
    if (tid == 0) {
        float ls = 0.f, cnt = 0.f;
        for (int k = 0; k < KRET; ++k) {
            int m = k + (k >= (i & (SPC - 1)) ? 1 : 0);
            if (s_posd[m] < s_negd[k] + MARGIN) {
                ls += (s_dreal[k] + MARGIN) + fmaxf(MARGIN - s_dreal[KRET + k], 0.f);
                cnt += 1.f;
            }
        }
        if (ls != 0.f) atomicAdd(&ws_acc[0], ls);
        if (cnt != 0.f) atomicAdd(&ws_acc[1], cnt);
    }
}

__global__ void finalize_ws(const float* __restrict__ ws_acc, float* __restrict__ out) {
    float ls = ws_acc[0], cnt = ws_acc[1];
    out[0] = cnt > 0.f ? ls / cnt : ls;
}

extern "C" void kernel_launch(void* const* d_in, const int* in_sizes, int n_in,
                              void* d_out, int out_size, void* d_ws, size_t ws_size,
                              hipStream_t stream) {
    const float* emb     = (const float*)d_in[0];
    const int*   labels  = (const int*)d_in[1];
    const float* emb1    = (const float*)d_in[2];
    const int*   labels1 = (const int*)d_in[3];
    float* ws = (float*)d_ws;

    const size_t need = (size_t)3850240 * sizeof(float);
    if (ws_size >= need) {
        float*  diag   = ws + 4096;
        float*  posd   = ws + 8192;
        ushort* embH   = (ushort*)(ws + 40960);
        ushort* emb1H  = (ushort*)(ws + 106496);
        u64*    cand   = (u64*)(ws + 172032);
        float*  rowls  = ws + 3842048;
        float*  rowcnt = ws + 3846144;

        prep_kernel<<<NROWS / 4, 256, 0, stream>>>(emb, emb1, embH, emb1H, diag);
        dim3 grid(NROWS / 128, NROWS / 128);
        dist_mfma<<<grid, 256, 0, stream>>>(embH, emb1H, labels, labels1, diag, posd, cand);
        merge_kernel<<<NROWS / 4, 256, 0, stream>>>(emb, posd, cand, rowls, rowcnt);
        finalize_kernel<<<1, 256, 0, stream>>>(rowls, rowcnt, (float*)d_out);
    } else {
        hipMemsetAsync(d_ws, 0, 2 * sizeof(float), stream);
        float* diag = ws + 2;
        diag_kernel<<<NROWS / 4, 256, 0, stream>>>(emb, emb1, diag);
        main_kernel<<<NROWS, 256, 0, stream>>>(emb, emb1, labels, labels1, diag, ws);
        finalize_ws<<<1, 1, 0, stream>>>(ws, (float*)d_out);
    }
}

// Round 7
// 48.507 us; speedup vs baseline: 4.6646x; 1.4668x over previous
//
#include <hip/hip_runtime.h>
#include <math.h>

#define NROWS 4096
#define D 128
#define SPC 8
#define KRET 7
#define MARGIN 0.2f
#define NTILE 32              // 4096/128 column tiles
#define CPT 14                // candidates per (row, tile): 2 quadrants x top-7
#define CPR (NTILE * CPT)     // 448 candidates per row

typedef unsigned long long u64;
typedef unsigned int u32;
typedef __attribute__((ext_vector_type(8))) short short8;   // 8 bf16 (4 VGPRs)
typedef __attribute__((ext_vector_type(4))) float f32x4;    // MFMA accumulator

__device__ __forceinline__ u64 minu(u64 a, u64 b) { return a < b ? a : b; }
__device__ __forceinline__ u32 minu32(u32 a, u32 b) { return a < b ? a : b; }
__device__ __forceinline__ u32 maxu32(u32 a, u32 b) { return a > b ? a : b; }

// bf16 round-to-nearest-even
__device__ __forceinline__ ushort f2bf_rne(float x) {
    unsigned u = __float_as_uint(x);
    unsigned r = (u + 0x7fffu + ((u >> 16) & 1u)) >> 16;
    return (ushort)r;
}

// ws layout (floats):
//   [0..1]               (fallback accums only)
//   [4096 .. 8191]       diag
//   [8192 .. 40959]      posd (4096 x 8 f32, stores clamped d^2)
//   [40960 .. 106495]    embH  (4096x128 bf16)
//   [106496 .. 172031]   emb1H (4096x128 bf16)
//   [172032 .. 2007039]  cand (u32, 4096 x 448)
//   [2007040 ..]         rowls (4096), rowcnt (4096)

// ---- prep: bf16 round of both matrices + exact f32 Gram diagonal ----
__global__ __launch_bounds__(256) void prep_kernel(const float* __restrict__ emb,
                                                   const float* __restrict__ emb1,
                                                   ushort* __restrict__ embH,
                                                   ushort* __restrict__ emb1H,
                                                   float* __restrict__ diag) {
    const int lane = threadIdx.x & 63;
    const int row = blockIdx.x * 4 + (threadIdx.x >> 6);
    const size_t base = (size_t)row * D + 2 * lane;
    const float2 a = *(const float2*)(emb + base);
    const float2 b = *(const float2*)(emb1 + base);

    *(ushort2*)(embH + base)  = make_ushort2(f2bf_rne(a.x), f2bf_rne(a.y));
    *(ushort2*)(emb1H + base) = make_ushort2(f2bf_rne(b.x), f2bf_rne(b.y));

    float s = a.x * b.x + a.y * b.y;
#pragma unroll
    for (int off = 1; off < 64; off <<= 1) s += __shfl_xor(s, off, 64);
    if (lane == 0) diag[row] = s;
}

// ---- dist tile via bf16 MFMA + fused per-quadrant top-7 (d^2-space, u32-packed) ----
// 128x128 tile, 4 waves, each wave owns a 64x64 quadrant (R,C).
__global__ __launch_bounds__(256, 4) void dist_mfma(const ushort* __restrict__ embH,
                                                    const ushort* __restrict__ emb1H,
                                                    const int* __restrict__ labels,
                                                    const int* __restrict__ labels1,
                                                    const float* __restrict__ diag,
                                                    float* __restrict__ posd, u32* __restrict__ cand) {
    __shared__ ushort smem[2][9216];      // AH, BH: [128][72] bf16 each
    __shared__ float sdA[128], sdB[128];
    __shared__ int sLi[128], sLj[128];
    __shared__ int s_lmin[4], s_lmax[4];
    ushort* AH = smem[0];
    ushort* BH = smem[1];
    ushort* distbuf = (ushort*)(void*)smem;   // [128][132] u16 bf16(d2) scores, overlays staging

    const int t = threadIdx.x;
    const int i0 = blockIdx.y * 128, j0 = blockIdx.x * 128;
    const int w = t >> 6, l = t & 63;

    {   // diag + labels -> LDS, plus per-wave label min/max for block-uniform pos gating
        int lab;
        if (t < 128) { sdA[t] = diag[i0 + t]; lab = labels1[i0 + t]; sLi[t] = lab; }
        else         { sdB[t - 128] = diag[j0 + t - 128]; lab = labels[j0 + t - 128]; sLj[t - 128] = lab; }
        int mn = lab, mx = lab;
#pragma unroll
        for (int off = 1; off < 64; off <<= 1) {
            mn = min(mn, __shfl_xor(mn, off, 64));
            mx = max(mx, __shfl_xor(mx, off, 64));
        }
        if (l == 0) { s_lmin[w] = mn; s_lmax[w] = mx; }
    }

    const int R = (w >> 1) * 64, C = (w & 1) * 64;
    const int lr = l & 15, lg = l >> 4;

    f32x4 acc[4][4];
#pragma unroll
    for (int m = 0; m < 4; ++m)
#pragma unroll
        for (int n = 0; n < 4; ++n) acc[m][n] = (f32x4){0.f, 0.f, 0.f, 0.f};

    bool hasPos = false;
    const int srow = t & 127;
    for (int p = 0; p < 2; ++p) {
        if (p) __syncthreads();            // phase-0 frag reads complete before restage
#pragma unroll
        for (int n = 0; n < 4; ++n) {
            const int c = n * 2 + (t >> 7);                         // 0..7
            const size_t gA = (size_t)(i0 + srow) * D + p * 64 + c * 8;
            const size_t gB = (size_t)(j0 + srow) * D + p * 64 + c * 8;
            const int ld = srow * 72 + c * 8;
            *(uint4*)(AH + ld) = *(const uint4*)(embH + gA);
            *(uint4*)(BH + ld) = *(const uint4*)(emb1H + gB);
        }
        __syncthreads();

        if (p == 0) {   // labels/diag now visible: block-uniform pos gate
            const int minLi = min(s_lmin[0], s_lmin[1]);
            const int maxLi = max(s_lmax[0], s_lmax[1]);
            const int minLj = min(s_lmin[2], s_lmin[3]);
            const int maxLj = max(s_lmax[2], s_lmax[3]);
            hasPos = !(maxLi < minLj || maxLj < minLi);
        }

#pragma unroll
        for (int ks = 0; ks < 2; ++ks) {
            const int koff = ks * 32 + lg * 8;
            short8 ah[4], bh[4];
#pragma unroll
            for (int m = 0; m < 4; ++m) {
                ah[m] = *(const short8*)(AH + (R + 16 * m + lr) * 72 + koff);
                bh[m] = *(const short8*)(BH + (C + 16 * m + lr) * 72 + koff);
            }
#pragma unroll
            for (int m = 0; m < 4; ++m)
#pragma unroll
                for (int n = 0; n < 4; ++n)
                    acc[m][n] = __builtin_amdgcn_mfma_f32_16x16x32_bf16(ah[m], bh[n], acc[m][n], 0, 0, 0);
        }
    }

    // preload diag slices to registers (sdA/sdB are NOT overlaid; safe across barrier)
    float sdA_r[16], sdB_c[4];
#pragma unroll
    for (int m = 0; m < 4; ++m)
#pragma unroll
        for (int r = 0; r < 4; ++r) sdA_r[m * 4 + r] = sdA[R + 16 * m + 4 * lg + r];
#pragma unroll
    for (int n = 0; n < 4; ++n) sdB_c[n] = sdB[C + 16 * n + lr];

    __syncthreads();   // all waves' frag reads done; staging area becomes score buf

    // epilogue: clamped d^2 -> bf16-RNE u16 scores in distbuf.
    // C/D layout (m89-verified): col = lane&15, row = (lane>>4)*4 + reg
    if (!hasPos) {
#pragma unroll
        for (int m = 0; m < 4; ++m)
#pragma unroll
            for (int n = 0; n < 4; ++n)
#pragma unroll
                for (int r = 0; r < 4; ++r) {
                    const int row = R + 16 * m + 4 * lg + r;
                    const int col = C + 16 * n + lr;
                    const float d2c = fmaxf(sdA_r[m * 4 + r] + sdB_c[n] - 2.f * acc[m][n][r], 1e-4f);
                    distbuf[row * 132 + col] = f2bf_rne(d2c);
                }
    } else {
        int sLi_r[16], sLj_c[4];
#pragma unroll
        for (int m = 0; m < 4; ++m)
#pragma unroll
            for (int r = 0; r < 4; ++r) sLi_r[m * 4 + r] = sLi[R + 16 * m + 4 * lg + r];
#pragma unroll
        for (int n = 0; n < 4; ++n) sLj_c[n] = sLj[C + 16 * n + lr];
#pragma unroll
        for (int m = 0; m < 4; ++m)
#pragma unroll
            for (int n = 0; n < 4; ++n)
#pragma unroll
                for (int r = 0; r < 4; ++r) {
                    const int row = R + 16 * m + 4 * lg + r;
                    const int col = C + 16 * n + lr;
                    const int gi = i0 + row, gj = j0 + col;
                    const float d2c = fmaxf(sdA_r[m * 4 + r] + sdB_c[n] - 2.f * acc[m][n][r], 1e-4f);
                    const bool pos = (sLj_c[n] == sLi_r[m * 4 + r]) && (gi != gj);
                    if (pos) posd[(size_t)gi * SPC + (gj & (SPC - 1))] = d2c;
                    distbuf[row * 132 + col] = pos ? (ushort)0xFFFFu : f2bf_rne(d2c);
                }
    }

    // wave-local sync: this wave's score writes cover exactly the quadrant it scans
    asm volatile("s_waitcnt lgkmcnt(0)" ::: "memory");
    __builtin_amdgcn_sched_barrier(0);

    // selection: 1 thread per row over this wave's 64 cols.
    // Branch-free sorted-7 chain on u32 (score16|col12): exact (score,col) lex order.
    {
        const int row = R + l;
        u32 s[KRET];
#pragma unroll
        for (int k = 0; k < KRET; ++k) s[k] = 0xFFFFFFFFu;
        const ushort* dr = distbuf + row * 132 + C;
        const u32 cbase = (u32)(j0 + C);
#pragma unroll 4
        for (int c = 0; c < 64; ++c) {
            const int cc = (c + row) & 63;            // diagonal stagger
            u32 pk = ((u32)dr[cc] << 16) | (cbase + cc);
#pragma unroll
            for (int k = 0; k < KRET; ++k) {
                const u32 lo = minu32(s[k], pk);
                pk = maxu32(s[k], pk);
                s[k] = lo;
            }
        }
        u32* cw = cand + (size_t)(i0 + row) * CPR + (j0 >> 7) * CPT + (C >> 6) * KRET;
#pragma unroll
        for (int k = 0; k < KRET; ++k) cw[k] = s[k];
    }
}

// ---- merge 448 u32 candidates/row -> global top-7, validity, loss. Wave per row. ----
__global__ __launch_bounds__(256) void merge_kernel(const float* __restrict__ emb,
                                                    const float* __restrict__ posd,
                                                    const u32* __restrict__ cand,
                                                    float* __restrict__ rowls,
                                                    float* __restrict__ rowcnt) {
    const int lane = threadIdx.x & 63;
    const int i = blockIdx.x * 4 + (threadIdx.x >> 6);
    const u32* cr = cand + (size_t)i * CPR;
    u32 e[7];
#pragma unroll
    for (int q = 0; q < 7; ++q) e[q] = cr[q * 64 + lane];

    u32 w[KRET];
#pragma unroll
    for (int r = 0; r < KRET; ++r) {
        u32 m = e[0];
#pragma unroll
        for (int q = 1; q < 7; ++q) m = minu32(m, e[q]);
#pragma unroll
        for (int off = 1; off < 64; off <<= 1) m = minu32(m, (u32)__shfl_xor((int)m, off, 64));
        w[r] = m;
#pragma unroll
        for (int q = 0; q < 7; ++q) e[q] = (e[q] == m) ? 0xFFFFFFFFu : e[q];
    }

    // sort winners by column index: rotate to (col12 << 20 | score16 << 4), Batcher-8
    u32 s[8];
#pragma unroll
    for (int r = 0; r < KRET; ++r) s[r] = (w[r] << 20) | (w[r] >> 12);
    s[7] = 0xFFFFFFFFu;
#define CE(x, y) { u32 lo = minu32(s[x], s[y]); u32 hi = maxu32(s[x], s[y]); s[x] = lo; s[y] = hi; }
    CE(0,1) CE(2,3) CE(4,5) CE(6,7)
    CE(0,2) CE(1,3) CE(4,6) CE(5,7)
    CE(1,2) CE(5,6)
    CE(0,4) CE(1,5) CE(2,6) CE(3,7)
    CE(2,4) CE(3,5)
    CE(1,2) CE(3,4) CE(5,6)
#undef CE

    const int ig = i & (SPC - 1);
    float ls = 0.f, cnt = 0.f;
    bool any = false;
    bool v[KRET];
    int nidx[KRET];
#pragma unroll
    for (int k = 0; k < KRET; ++k) {
        nidx[k] = (int)(s[k] >> 20);
        const float d2n = __uint_as_float(((s[k] >> 4) & 0xFFFF0u) << 12);  // score16 << 16
        const float dneg = sqrtf(d2n);
        const int m = k + (k >= ig ? 1 : 0);
        const float dp = sqrtf(posd[(size_t)i * SPC + m]);
        v[k] = dp < dneg + MARGIN;       // wave-uniform
        any = any || v[k];
    }

    if (any) {
        const float a0 = emb[(size_t)i * D + lane];
        const float a1 = emb[(size_t)i * D + 64 + lane];
#pragma unroll
        for (int k = 0; k < KRET; ++k) {
            if (v[k]) {
                const int m = k + (k >= ig ? 1 : 0);
                const int tp = (i & ~(SPC - 1)) + m;
                const int tn = nidx[k];
                float d0 = emb[(size_t)tp * D + lane] - a0;
                float d1 = emb[(size_t)tp * D + 64 + lane] - a1;
                float sp = d0 * d0 + d1 * d1;
                float g0 = emb[(size_t)tn * D + lane] - a0;
                float g1 = emb[(size_t)tn * D + 64 + lane] - a1;
                float sn = g0 * g0 + g1 * g1;
#pragma unroll
                for (int off = 1; off < 64; off <<= 1) {
                    sp += __shfl_xor(sp, off, 64);
                    sn += __shfl_xor(sn, off, 64);
                }
                ls += (sqrtf(sp + 1e-8f) + MARGIN) + fmaxf(MARGIN - sqrtf(sn + 1e-8f), 0.f);
                cnt += 1.f;
            }
        }
    }
    if (lane == 0) {           // always write: poison-safe, deterministic
        rowls[i] = ls;
        rowcnt[i] = cnt;
    }
}

// ---- deterministic single-block reduction over 4096 per-row partials ----
__global__ __launch_bounds__(256) void finalize_kernel(const float* __restrict__ rowls,
                                                       const float* __restrict__ rowcnt,
                                                       float* __restrict__ out) {
    const int t = threadIdx.x;
    __shared__ float sls[4], scnt[4];
    float ls = 0.f, cnt = 0.f;
#pragma unroll
    for (int q = 0; q < NROWS / 256; ++q) {
        ls += rowls[q * 256 + t];
        cnt += rowcnt[q * 256 + t];
    }
#pragma unroll
    for (int off = 1; off < 64; off <<= 1) {
        ls += __shfl_xor(ls, off, 64);
        cnt += __shfl_xor(cnt, off, 64);
    }
    if ((t & 63) == 0) { sls[t >> 6] = ls; scnt[t >> 6] = cnt; }
    __syncthreads();
    if (t == 0) {
        float L = sls[0] + sls[1] + sls[2] + sls[3];
        float C = scnt[0] + scnt[1] + scnt[2] + scnt[3];
        out[0] = C > 0.f ? L / C : L;
    }
}

// ---------------- Fallback path (round-1, only if ws too small) ----------------
__global__ __launch_bounds__(256) void diag_kernel(const float* __restrict__ emb,
                                                   const float* __restrict__ emb1,
                                                   float* __restrict__ diag) {
    int wave = threadIdx.x >> 6;
    int lane = threadIdx.x & 63;
    int row = blockIdx.x * 4 + wave;
    const float* a = emb + (size_t)row * D;
    const float* b = emb1 + (size_t)row * D;
    float s = a[lane] * b[lane] + a[lane + 64] * b[lane + 64];
    for (int off = 32; off > 0; off >>= 1) s += __shfl_down(s, off, 64);
    if (lane == 0) diag[row] = s;
}

__global__ __launch_bounds__(256) void main_kernel(const float* __restrict__ emb,
                                                   const float* __restrict__ emb1,
                                                   const int* __restrict__ labels,
                                                   const int* __restrict__ labels1,
                                                   const float* __restrict__ diag,
                                                   float* __restrict__ ws_acc) {
    const int i = blockIdx.x;
    const int tid = threadIdx.x;
    __shared__ float s_anchor[D];
    __shared__ float s_posd[SPC];
    __shared__ u64 s_red[4];
    __shared__ u64 s_win;
    __shared__ int s_negidx[KRET];
    __shared__ float s_negd[KRET];
    __shared__ float s_dreal[2 * KRET];

    if (tid < D) s_anchor[tid] = emb[(size_t)i * D + tid];
    __syncthreads();
    const float diag_i = diag[i];
    const int li = labels1[i];
    float score[16];
#pragma unroll
    for (int it = 0; it < 16; ++it) {
        int j = it * 256 + tid;
        const float4* r = (const float4*)(emb1 + (size_t)j * D);
        float acc = 0.f;
#pragma unroll
        for (int q = 0; q < D / 4; ++q) {
            float4 vv = r[q];
            acc = fmaf(vv.x, s_anchor[4 * q + 0], acc);
            acc = fmaf(vv.y, s_anchor[4 * q + 1], acc);
            acc = fmaf(vv.z, s_anchor[4 * q + 2], acc);
            acc = fmaf(vv.w, s_anchor[4 * q + 3], acc);
        }
        float d2 = diag_i + diag[j] - 2.f * acc;
        float dist = sqrtf(fmaxf(d2, 1e-4f));
        bool is_pos = (labels[j] == li) && (j != i);
        if (is_pos) s_posd[j & (SPC - 1)] = dist;
        score[it] = dist + (is_pos ? 1e6f : 0.f);
    }
    __syncthreads();
    for (int r = 0; r < KRET; ++r) {
        u64 best = ~0ull;
#pragma unroll
        for (int it = 0; it < 16; ++it) {
            u64 p = ((u64)__float_as_uint(score[it]) << 32) | (unsigned)(it * 256 + tid);
            best = best < p ? best : p;
        }
        for (int off = 32; off > 0; off >>= 1) {
            u64 o = __shfl_down(best, off, 64);
            best = best < o ? best : o;
        }
        if ((tid & 63) == 0) s_red[tid >> 6] = best;
        __syncthreads();
        if (tid == 0) {
            u64 w2 = s_red[0];
            w2 = w2 < s_red[1] ? w2 : s_red[1];
            w2 = w2 < s_red[2] ? w2 : s_red[2];
            w2 = w2 < s_red[3] ? w2 : s_red[3];
            s_win = w2;
        }
        __syncthreads();
        u64 w2 = s_win;
        int cj = (int)(w2 & 0xffffffffu);
        if (tid == (cj & 255)) score[cj >> 8] = 1e30f;
        if (tid == 0) { s_negidx[r] = cj; s_negd[r] = __uint_as_float((unsigned)(w2 >> 32)); }
        __syncthreads();
    }
    if (tid == 0) {
        for (int a = 1; a < KRET; ++a) {
            int ix = s_negidx[a]; float dv = s_negd[a];
            int b = a - 1;
            while (b >= 0 && s_negidx[b] > ix) {
                s_negidx[b + 1] = s_negidx[b]; s_negd[b + 1] = s_negd[b]; --b;
            }
            s_negidx[b + 1] = ix; s_negd[b + 1] = dv;
        }
    }
    __syncthreads();
    {
        int wave = tid >> 6, lane = tid & 63;
        int gb = i & ~(SPC - 1);
        for (int p = wave; p < 2 * KRET; p += 4) {
            int tgt;
            if (p < KRET) {
                int k = p;
                int m = k + (k >= (i & (SPC - 1)) ? 1 : 0);
                tgt = gb + m;
            } else tgt = s_negidx[p - KRET];
            float d0 = emb[(size_t)tgt * D + lane] - s_anchor[lane];
            float d1 = emb[(size_t)tgt * D + 64 + lane] - s_anchor[64 + lane];
            float s = d0 * d0 + d1 * d1;
            for (int off = 32; off > 0; off >>= 1) s += __shfl_down(s, off, 64);
            if (lane == 0) s_dreal[p] = sqrtf(s + 1e-8f);
        }
    }
    __syncthreads();
    if (tid == 0) {
        float ls = 0.f, cnt = 0.f;
        for (int k = 0; k < KRET; ++k) {
            int m = k + (k >= (i & (SPC - 1)) ? 1 : 0);
            if (s_posd[m] < s_negd[k] + MARGIN) {
                ls += (s_dreal[k] + MARGIN) + fmaxf(MARGIN - s_dreal[KRET + k], 0.f);
                cnt += 1.f;
            }
        }
        if (ls != 0.f) atomicAdd(&ws_acc[0], ls);
        if (cnt != 0.f) atomicAdd(&ws_acc[1], cnt);
    }
}

__global__ void finalize_ws(const float* __restrict__ ws_acc, float* __restrict__ out) {
    float ls = ws_acc[0], cnt = ws_acc[1];
    out[0] = cnt > 0.f ? ls / cnt : ls;
}

extern "C" void kernel_launch(void* const* d_in, const int* in_sizes, int n_in,
                              void* d_out, int out_size, void* d_ws, size_t ws_size,
                              hipStream_t stream) {
    const float* emb     = (const float*)d_in[0];
    const int*   labels  = (const int*)d_in[1];
    const float* emb1    = (const float*)d_in[2];
    const int*   labels1 = (const int*)d_in[3];
    float* ws = (float*)d_ws;

    const size_t need = (size_t)2015232 * sizeof(float);
    if (ws_size >= need) {
        float*  diag   = ws + 4096;
        float*  posd   = ws + 8192;
        ushort* embH   = (ushort*)(ws + 40960);
        ushort* emb1H  = (ushort*)(ws + 106496);
        u32*    cand   = (u32*)(ws + 172032);
        float*  rowls  = ws + 2007040;
        float*  rowcnt = ws + 2011136;

        prep_kernel<<<NROWS / 4, 256, 0, stream>>>(emb, emb1, embH, emb1H, diag);
        dim3 grid(NROWS / 128, NROWS / 128);
        dist_mfma<<<grid, 256, 0, stream>>>(embH, emb1H, labels, labels1, diag, posd, cand);
        merge_kernel<<<NROWS / 4, 256, 0, stream>>>(emb, posd, cand, rowls, rowcnt);
        finalize_kernel<<<1, 256, 0, stream>>>(rowls, rowcnt, (float*)d_out);
    } else {
        hipMemsetAsync(d_ws, 0, 2 * sizeof(float), stream);
        float* diag = ws + 2;
        diag_kernel<<<NROWS / 4, 256, 0, stream>>>(emb, emb1, diag);
        main_kernel<<<NROWS, 256, 0, stream>>>(emb, emb1, labels, labels1, diag, ws);
        finalize_ws<<<1, 1, 0, stream>>>(ws, (float*)d_out);
    }
}